// Round 3
// baseline (1730.073 us; speedup 1.0000x reference)
//
#include <hip/hip_runtime.h>

#define NEG_SLOPE 0.2f

// ---------------- bf16 helpers ----------------
__device__ __forceinline__ float bf2f(unsigned short u) {
    return __uint_as_float(((unsigned int)u) << 16);
}
__device__ __forceinline__ unsigned short f2bf(float f) {
    unsigned int x = __float_as_uint(f);
    x += 0x7fffu + ((x >> 16) & 1u);  // round-to-nearest-even
    return (unsigned short)(x >> 16);
}

__device__ __forceinline__ void load4(const float* p, float o[4]) {
    float4 v = *(const float4*)p;
    o[0] = v.x; o[1] = v.y; o[2] = v.z; o[3] = v.w;
}
__device__ __forceinline__ void load4(const unsigned short* p, float o[4]) {
    ushort4 v = *(const ushort4*)p;
    o[0] = bf2f(v.x); o[1] = bf2f(v.y); o[2] = bf2f(v.z); o[3] = bf2f(v.w);
}
__device__ __forceinline__ float ld1(const float* p) { return *p; }
__device__ __forceinline__ float ld1(const unsigned short* p) { return bf2f(*p); }
__device__ __forceinline__ void st1(float* p, float v) { *p = v; }
__device__ __forceinline__ void st1(unsigned short* p, float v) { *p = f2bf(v); }

// ============================ fold kernels ============================
// layer1: out[d*8+h] = sum_c W[d,512][h*64+c] * av[h*64+c]
__global__ void fold1_kernel(const float* __restrict__ W, const float* __restrict__ av,
                             float* __restrict__ out) {
    int t = blockIdx.x * blockDim.x + threadIdx.x;
    if (t >= 128 * 8) return;
    int d = t >> 3, h = t & 7;
    const float* wr = W + d * 512 + h * 64;
    const float* ar = av + h * 64;
    float s = 0.f;
#pragma unroll
    for (int c = 0; c < 64; ++c) s = fmaf(wr[c], ar[c], s);
    out[t] = s;
}

// layer2 fold: out[d] = sum_c W[d*64+c]*av[c]   (W [512,64], av [64])
__global__ void fold2_kernel(const float* __restrict__ W, const float* __restrict__ av,
                             float* __restrict__ out) {
    int d = blockIdx.x * blockDim.x + threadIdx.x;
    if (d >= 512) return;
    const float* wr = W + d * 64;
    float s = 0.f;
#pragma unroll
    for (int c = 0; c < 64; ++c) s = fmaf(wr[c], av[c], s);
    out[d] = s;
}

// ============================ skinny projections ============================
// layer1: per node n (one wave): outA[n*8+h] = sum_d X[n,d]*wA[d*8+h]; same for B.
__global__ __launch_bounds__(256) void skinny1_kernel(
    const float* __restrict__ X, int N,
    const float* __restrict__ wA, const float* __restrict__ wB,
    float* __restrict__ outA, float* __restrict__ outB) {
    int w = (blockIdx.x * 256 + threadIdx.x) >> 6;
    int lane = threadIdx.x & 63;
    if (w >= N) return;
    float x0 = X[(size_t)w * 128 + lane];
    float x1 = X[(size_t)w * 128 + 64 + lane];
#pragma unroll
    for (int h = 0; h < 8; ++h) {
        float vA = x0 * wA[lane * 8 + h] + x1 * wA[(64 + lane) * 8 + h];
        float vB = x0 * wB[lane * 8 + h] + x1 * wB[(64 + lane) * 8 + h];
#pragma unroll
        for (int off = 32; off > 0; off >>= 1) {
            vA += __shfl_xor(vA, off);
            vB += __shfl_xor(vB, off);
        }
        if (lane == 0) { outA[(size_t)w * 8 + h] = vA; outB[(size_t)w * 8 + h] = vB; }
    }
}

// layer2: per node n (one wave): outA[n] = dot(X[n,:512], wa); outB[n] = dot(X[n,:512], wb)
template <typename XT>
__global__ __launch_bounds__(256) void skinny2_kernel(
    const XT* __restrict__ X, int N,
    const float* __restrict__ wa, const float* __restrict__ wb,
    float* __restrict__ outA, float* __restrict__ outB) {
    int w = (blockIdx.x * 256 + threadIdx.x) >> 6;
    int lane = threadIdx.x & 63;
    if (w >= N) return;
    float a = 0.f, b = 0.f;
#pragma unroll
    for (int i = 0; i < 8; ++i) {
        float x = ld1(X + (size_t)w * 512 + i * 64 + lane);
        a = fmaf(x, wa[i * 64 + lane], a);
        b = fmaf(x, wb[i * 64 + lane], b);
    }
#pragma unroll
    for (int off = 32; off > 0; off >>= 1) {
        a += __shfl_xor(a, off);
        b += __shfl_xor(b, off);
    }
    if (lane == 0) { outA[w] = a; outB[w] = b; }
}

// ============================ CSR build ============================
__global__ void hist_kernel(const int* __restrict__ dst, int E, int* __restrict__ deg) {
    int i = blockIdx.x * blockDim.x + threadIdx.x;
    if (i < E) atomicAdd(&deg[dst[i]], 1);
}

__global__ __launch_bounds__(512) void scan_chunk_kernel(const int* __restrict__ in, int N,
                                                         int* __restrict__ incl, int* __restrict__ sums) {
    __shared__ int sm[512];
    int i = blockIdx.x * 512 + threadIdx.x;
    int v = (i < N) ? in[i] : 0;
    sm[threadIdx.x] = v;
    __syncthreads();
    for (int off = 1; off < 512; off <<= 1) {
        int t = (threadIdx.x >= off) ? sm[threadIdx.x - off] : 0;
        __syncthreads();
        sm[threadIdx.x] += t;
        __syncthreads();
    }
    if (i < N) incl[i] = sm[threadIdx.x];
    if (threadIdx.x == 511) sums[blockIdx.x] = sm[511];
}

__global__ __launch_bounds__(512) void scan_sums_kernel(int* __restrict__ sums, int n) {
    __shared__ int sm[512];
    int v = (threadIdx.x < n) ? sums[threadIdx.x] : 0;
    sm[threadIdx.x] = v;
    __syncthreads();
    for (int off = 1; off < 512; off <<= 1) {
        int t = (threadIdx.x >= off) ? sm[threadIdx.x - off] : 0;
        __syncthreads();
        sm[threadIdx.x] += t;
        __syncthreads();
    }
    if (threadIdx.x < n) sums[threadIdx.x] = sm[threadIdx.x] - v;  // exclusive chunk offset
}

__global__ void scan_fin_kernel(const int* __restrict__ incl, const int* __restrict__ deg,
                                const int* __restrict__ sums, int N,
                                int* __restrict__ rowptr, int* __restrict__ cursor) {
    int i = blockIdx.x * blockDim.x + threadIdx.x;
    if (i >= N) return;
    int excl = incl[i] - deg[i] + sums[i >> 9];
    rowptr[i] = excl;
    cursor[i] = excl;
}

__global__ void scatter_kernel(const int* __restrict__ src, const int* __restrict__ dst, int E,
                               int* __restrict__ cursor, int* __restrict__ csr_src) {
    int i = blockIdx.x * blockDim.x + threadIdx.x;
    if (i >= E) return;
    int pos = atomicAdd(&cursor[dst[i]], 1);
    csr_src[pos] = src[i];
}

// ============================ aggregation (online softmax) ============================
// layer1: one wave per (dst,head). hsrc [Nsrc,512]; alsrc [Nsrc,8]; aldst [Ndst,8].
template <typename OT>
__global__ __launch_bounds__(256) void agg1_kernel(
    const int* __restrict__ rowptr, const int* __restrict__ deg, const int* __restrict__ csr_src,
    const float* __restrict__ hsrc, const float* __restrict__ alsrc, const float* __restrict__ aldst,
    const float* __restrict__ bias, OT* __restrict__ out, int Ndst) {
    int w = (blockIdx.x * 256 + threadIdx.x) >> 6;
    int lane = threadIdx.x & 63;
    int n = w >> 3, h = w & 7;
    if (n >= Ndst) return;
    int start = rowptr[n], cnt = deg[n];
    float ald = aldst[(size_t)n * 8 + h];
    float m = -INFINITY, s = 0.f, acc = 0.f;
    for (int i = 0; i < cnt; ++i) {
        int sp = csr_src[start + i];
        float e = alsrc[(size_t)sp * 8 + h] + ald;
        e = (e > 0.f) ? e : NEG_SLOPE * e;
        float hv = hsrc[(size_t)sp * 512 + h * 64 + lane];
        if (e > m) {
            float sc = __expf(m - e);
            s *= sc; acc *= sc; m = e;
        }
        float p = __expf(e - m);
        s += p;
        acc = fmaf(p, hv, acc);
    }
    float r = acc / (s + 1e-16f);
    float o = fmaxf(r + bias[h * 64 + lane], 0.f);
    st1(&out[(size_t)n * 512 + h * 64 + lane], o);
}

// layer2 (H=1,C=64): one wave per dst node. hsrc [Nsrc,64]; alsrc [Nsrc]; aldst [Ndst].
__global__ __launch_bounds__(256) void agg2_kernel(
    const int* __restrict__ rowptr, const int* __restrict__ deg, const int* __restrict__ csr_src,
    const float* __restrict__ hsrc, const float* __restrict__ alsrc, const float* __restrict__ aldst,
    const float* __restrict__ bias, float* __restrict__ out, int Ndst) {
    int w = (blockIdx.x * 256 + threadIdx.x) >> 6;
    int lane = threadIdx.x & 63;
    if (w >= Ndst) return;
    int start = rowptr[w], cnt = deg[w];
    float ald = aldst[w];
    float m = -INFINITY, s = 0.f, acc = 0.f;
    for (int i = 0; i < cnt; ++i) {
        int sp = csr_src[start + i];
        float e = alsrc[sp] + ald;
        e = (e > 0.f) ? e : NEG_SLOPE * e;
        float hv = hsrc[(size_t)sp * 64 + lane];
        if (e > m) {
            float sc = __expf(m - e);
            s *= sc; acc *= sc; m = e;
        }
        float p = __expf(e - m);
        s += p;
        acc = fmaf(p, hv, acc);
    }
    out[(size_t)w * 64 + lane] = fmaxf(acc / (s + 1e-16f) + bias[lane], 0.f);
}

// ============================ tiled GEMM (A may be f32 or bf16) ============================
// C[M,N] = A[M,K] @ B[K,N] (+bias). Row-major packed. K%32==0, N%4==0.
template <typename AT>
__global__ __launch_bounds__(256) void gemm_kernel(
    const AT* __restrict__ A, const float* __restrict__ B, float* __restrict__ C,
    const float* __restrict__ bias, int M, int N, int K) {
    const int BM = 64, BN = 64, BK = 32, LDT = 68;
    __shared__ float As[BK][LDT];
    __shared__ float Bs[BK][LDT];
    int tid = threadIdx.x;
    int tx = tid & 15, ty = tid >> 4;
    int m0 = blockIdx.y * BM, n0 = blockIdx.x * BN;
    float acc[4][4] = {};
    for (int k0 = 0; k0 < K; k0 += BK) {
        // A tile 64x32, transposed into As[k][m]
        {
            int c4 = (tid & 7) * 4;
            int r = tid >> 3;  // 0..31
#pragma unroll
            for (int rr = 0; rr < 2; ++rr) {
                int row = r + rr * 32;
                float v[4] = {0.f, 0.f, 0.f, 0.f};
                int gm = m0 + row;
                if (gm < M) load4(A + (size_t)gm * K + k0 + c4, v);
                As[c4 + 0][row] = v[0];
                As[c4 + 1][row] = v[1];
                As[c4 + 2][row] = v[2];
                As[c4 + 3][row] = v[3];
            }
        }
        // B tile 32x64
        {
            int c4 = (tid & 15) * 4;
            int r = tid >> 4;  // 0..15
#pragma unroll
            for (int rr = 0; rr < 2; ++rr) {
                int row = r + rr * 16;
                float4 v = *(const float4*)&B[(size_t)(k0 + row) * N + n0 + c4];
                *(float4*)&Bs[row][c4] = v;
            }
        }
        __syncthreads();
#pragma unroll
        for (int k = 0; k < BK; ++k) {
            float a[4], b[4];
            *(float4*)a = *(const float4*)&As[k][ty * 4];
            *(float4*)b = *(const float4*)&Bs[k][tx * 4];
#pragma unroll
            for (int i = 0; i < 4; ++i)
#pragma unroll
                for (int j = 0; j < 4; ++j) acc[i][j] = fmaf(a[i], b[j], acc[i][j]);
        }
        __syncthreads();
    }
#pragma unroll
    for (int i = 0; i < 4; ++i) {
        int gm = m0 + ty * 4 + i;
        if (gm >= M) continue;
#pragma unroll
        for (int j = 0; j < 4; ++j) {
            int gn = n0 + tx * 4 + j;
            float v = acc[i][j];
            if (bias) v += bias[gn];
            C[(size_t)gm * N + gn] = v;
        }
    }
}

// ============================ host launch ============================
static inline size_t align_up(size_t x, size_t a) { return (x + a - 1) / a * a; }

template <typename T>
static void mid_stage(  // everything between "h1_ts ready" and "h2 buffers ready"
    T* p1, T* t1, float* H,
    const float* x_p, const float* W1_pt,
    const int* rowptr_p, const int* deg_p, const int* csr_tp,
    const int* rowptr_t, const int* deg_t, const int* csr_pt,
    const float* als_tp, const float* ald_tp, const float* b1_tp,
    const float* als_pt, const float* ald_pt, const float* b1_pt,
    const float* W2_tp, const float* W2_pt,
    const float* was2_tp, const float* wad2_tp, const float* was2_pt, const float* wad2_pt,
    float* als2_tp, float* ald2_pt, float* als2_pt, float* ald2_tp,
    float* h2_ts, float* h2_ps,
    int Nt, int Np, hipStream_t stream) {
    // agg1 p: h1_ts currently in H
    agg1_kernel<T><<<(Np * 8 + 3) / 4, 256, 0, stream>>>(rowptr_p, deg_p, csr_tp, H, als_tp, ald_tp, b1_tp, p1, Np);
    // h1_ps into H (h1_ts dead)
    gemm_kernel<float><<<dim3(8, (Np + 63) / 64), 256, 0, stream>>>(x_p, W1_pt, H, nullptr, Np, 512, 128);
    // agg1 t
    agg1_kernel<T><<<(Nt * 8 + 3) / 4, 256, 0, stream>>>(rowptr_t, deg_t, csr_pt, H, als_pt, ald_pt, b1_pt, t1, Nt);
    // layer2 skinny projections
    skinny2_kernel<T><<<(Nt + 3) / 4, 256, 0, stream>>>(t1, Nt, was2_tp, wad2_pt, als2_tp, ald2_pt);
    skinny2_kernel<T><<<(Np + 3) / 4, 256, 0, stream>>>(p1, Np, was2_pt, wad2_tp, als2_pt, ald2_tp);
    // layer2 GEMMs into H-head region (h1_ps dead)
    gemm_kernel<T><<<dim3(1, (Nt + 63) / 64), 256, 0, stream>>>(t1, W2_tp, h2_ts, nullptr, Nt, 64, 512);
    gemm_kernel<T><<<dim3(1, (Np + 63) / 64), 256, 0, stream>>>(p1, W2_pt, h2_ps, nullptr, Np, 64, 512);
}

extern "C" void kernel_launch(void* const* d_in, const int* in_sizes, int n_in,
                              void* d_out, int out_size, void* d_ws, size_t ws_size,
                              hipStream_t stream) {
    const float* x_t = (const float*)d_in[0];
    const float* x_p = (const float*)d_in[1];
    const int* e_tp = (const int*)d_in[2];
    const int* e_pt = (const int*)d_in[3];
    const float* W1_tp = (const float*)d_in[4];
    const float* as1_tp = (const float*)d_in[5];
    const float* ad1_tp = (const float*)d_in[6];
    const float* b1_tp = (const float*)d_in[7];
    const float* W1_pt = (const float*)d_in[8];
    const float* as1_pt = (const float*)d_in[9];
    const float* ad1_pt = (const float*)d_in[10];
    const float* b1_pt = (const float*)d_in[11];
    const float* W2_tp = (const float*)d_in[12];
    const float* as2_tp = (const float*)d_in[13];
    const float* ad2_tp = (const float*)d_in[14];
    const float* b2_tp = (const float*)d_in[15];
    const float* W2_pt = (const float*)d_in[16];
    const float* as2_pt = (const float*)d_in[17];
    const float* ad2_pt = (const float*)d_in[18];
    const float* b2_pt = (const float*)d_in[19];
    const float* Wo_t = (const float*)d_in[20];
    const float* bo_t = (const float*)d_in[21];
    const float* Wo_p = (const float*)d_in[22];
    const float* bo_p = (const float*)d_in[23];

    const int Nt = in_sizes[0] / 128;
    const int Np = in_sizes[1] / 128;
    const int Etp = in_sizes[2] / 2;
    const int Ept = in_sizes[3] / 2;
    const size_t maxN = (Nt > Np) ? (size_t)Nt : (size_t)Np;

    // ---- workspace carve: small fixed stuff first ----
    char* p = (char*)d_ws;
    auto alloc = [&](size_t bytes) -> void* {
        void* r = (void*)p;
        p += align_up(bytes, 256);
        return r;
    };
    float* als_tp = (float*)alloc((size_t)Nt * 8 * 4);
    float* ald_pt = (float*)alloc((size_t)Nt * 8 * 4);
    float* als_pt = (float*)alloc((size_t)Np * 8 * 4);
    float* ald_tp = (float*)alloc((size_t)Np * 8 * 4);
    float* als2_tp = (float*)alloc((size_t)Nt * 4);
    float* ald2_pt = (float*)alloc((size_t)Nt * 4);
    float* als2_pt = (float*)alloc((size_t)Np * 4);
    float* ald2_tp = (float*)alloc((size_t)Np * 4);
    float* was1_tp = (float*)alloc(128 * 8 * 4);
    float* wad1_tp = (float*)alloc(128 * 8 * 4);
    float* was1_pt = (float*)alloc(128 * 8 * 4);
    float* wad1_pt = (float*)alloc(128 * 8 * 4);
    float* was2_tp = (float*)alloc(512 * 4);
    float* wad2_tp = (float*)alloc(512 * 4);
    float* was2_pt = (float*)alloc(512 * 4);
    float* wad2_pt = (float*)alloc(512 * 4);
    int* deg_p = (int*)alloc((size_t)Np * 4);
    int* rowptr_p = (int*)alloc((size_t)Np * 4);
    int* cur_p = (int*)alloc((size_t)Np * 4);
    int* incl_p = (int*)alloc((size_t)Np * 4);
    int* deg_t = (int*)alloc((size_t)Nt * 4);
    int* rowptr_t = (int*)alloc((size_t)Nt * 4);
    int* cur_t = (int*)alloc((size_t)Nt * 4);
    int* incl_t = (int*)alloc((size_t)Nt * 4);
    int* csr_tp = (int*)alloc((size_t)Etp * 4);
    int* csr_pt = (int*)alloc((size_t)Ept * 4);
    int* sums_p = (int*)alloc(512 * 4);
    int* sums_t = (int*)alloc(512 * 4);

    // big shared h1/h2 buffer
    float* H = (float*)alloc(maxN * 512 * 4);
    // layer2 sub-buffers live inside H (h1 values are dead by then)
    float* h2_ts = H;                                   // [Nt,64]
    float* h2_ps = H + (size_t)Nt * 64;                 // [Np,64]
    float* p2 = H + (size_t)Nt * 64 + (size_t)Np * 64;  // [Np,64]
    float* t2 = p2 + (size_t)Np * 64;                   // [Nt,64]

    size_t used = (size_t)(p - (char*)d_ws);
    size_t need_f32 = align_up((size_t)Np * 512 * 4, 256) + align_up((size_t)Nt * 512 * 4, 256);
    size_t need_bf16 = align_up((size_t)Np * 512 * 2, 256) + align_up((size_t)Nt * 512 * 2, 256);
    bool f32path;
    if (ws_size >= used + need_f32) f32path = true;
    else if (ws_size >= used + need_bf16) f32path = false;
    else return;  // ws too small: leave d_out poisoned -> clean absmax failure as diagnostic

    float* out_t = (float*)d_out;
    float* out_p = (float*)d_out + (size_t)Nt * 128;

    // ---- 0. zero degree arrays ----
    hipMemsetAsync(deg_p, 0, (size_t)Np * 4, stream);
    hipMemsetAsync(deg_t, 0, (size_t)Nt * 4, stream);

    // ---- 1. folds (both layers) + layer1 skinny projections ----
    fold1_kernel<<<4, 256, 0, stream>>>(W1_tp, as1_tp, was1_tp);
    fold1_kernel<<<4, 256, 0, stream>>>(W1_tp, ad1_tp, wad1_tp);
    fold1_kernel<<<4, 256, 0, stream>>>(W1_pt, as1_pt, was1_pt);
    fold1_kernel<<<4, 256, 0, stream>>>(W1_pt, ad1_pt, wad1_pt);
    fold2_kernel<<<2, 256, 0, stream>>>(W2_tp, as2_tp, was2_tp);
    fold2_kernel<<<2, 256, 0, stream>>>(W2_tp, ad2_tp, wad2_tp);
    fold2_kernel<<<2, 256, 0, stream>>>(W2_pt, as2_pt, was2_pt);
    fold2_kernel<<<2, 256, 0, stream>>>(W2_pt, ad2_pt, wad2_pt);
    skinny1_kernel<<<(Nt + 3) / 4, 256, 0, stream>>>(x_t, Nt, was1_tp, wad1_pt, als_tp, ald_pt);
    skinny1_kernel<<<(Np + 3) / 4, 256, 0, stream>>>(x_p, Np, was1_pt, wad1_tp, als_pt, ald_tp);

    // ---- 2. CSR build (dst-sorted), reused by both layers ----
    hist_kernel<<<(Etp + 255) / 256, 256, 0, stream>>>(e_tp + Etp, Etp, deg_p);
    hist_kernel<<<(Ept + 255) / 256, 256, 0, stream>>>(e_pt + Ept, Ept, deg_t);
    int nchp = (Np + 511) / 512, ncht = (Nt + 511) / 512;
    scan_chunk_kernel<<<nchp, 512, 0, stream>>>(deg_p, Np, incl_p, sums_p);
    scan_sums_kernel<<<1, 512, 0, stream>>>(sums_p, nchp);
    scan_fin_kernel<<<(Np + 255) / 256, 256, 0, stream>>>(incl_p, deg_p, sums_p, Np, rowptr_p, cur_p);
    scan_chunk_kernel<<<ncht, 512, 0, stream>>>(deg_t, Nt, incl_t, sums_t);
    scan_sums_kernel<<<1, 512, 0, stream>>>(sums_t, ncht);
    scan_fin_kernel<<<(Nt + 255) / 256, 256, 0, stream>>>(incl_t, deg_t, sums_t, Nt, rowptr_t, cur_t);
    scatter_kernel<<<(Etp + 255) / 256, 256, 0, stream>>>(e_tp, e_tp + Etp, Etp, cur_p, csr_tp);
    scatter_kernel<<<(Ept + 255) / 256, 256, 0, stream>>>(e_pt, e_pt + Ept, Ept, cur_t, csr_pt);

    // ---- 3. h1_ts = x_t @ W1_tp into H ----
    gemm_kernel<float><<<dim3(8, (Nt + 63) / 64), 256, 0, stream>>>(x_t, W1_tp, H, nullptr, Nt, 512, 128);

    // ---- 4..6. precision-adaptive middle ----
    if (f32path) {
        float* p1 = (float*)alloc((size_t)Np * 512 * 4);
        float* t1 = (float*)alloc((size_t)Nt * 512 * 4);
        mid_stage<float>(p1, t1, H, x_p, W1_pt,
                         rowptr_p, deg_p, csr_tp, rowptr_t, deg_t, csr_pt,
                         als_tp, ald_tp, b1_tp, als_pt, ald_pt, b1_pt,
                         W2_tp, W2_pt, was2_tp, wad2_tp, was2_pt, wad2_pt,
                         als2_tp, ald2_pt, als2_pt, ald2_tp, h2_ts, h2_ps, Nt, Np, stream);
    } else {
        unsigned short* p1 = (unsigned short*)alloc((size_t)Np * 512 * 2);
        unsigned short* t1 = (unsigned short*)alloc((size_t)Nt * 512 * 2);
        mid_stage<unsigned short>(p1, t1, H, x_p, W1_pt,
                                  rowptr_p, deg_p, csr_tp, rowptr_t, deg_t, csr_pt,
                                  als_tp, ald_tp, b1_tp, als_pt, ald_pt, b1_pt,
                                  W2_tp, W2_pt, was2_tp, wad2_tp, was2_pt, wad2_pt,
                                  als2_tp, ald2_pt, als2_pt, ald2_tp, h2_ts, h2_ps, Nt, Np, stream);
    }

    // ---- 7. layer2 aggregation (bias+relu fused) ----
    agg2_kernel<<<(Np + 3) / 4, 256, 0, stream>>>(rowptr_p, deg_p, csr_tp, h2_ts, als2_tp, ald2_tp, b2_tp, p2, Np);
    agg2_kernel<<<(Nt + 3) / 4, 256, 0, stream>>>(rowptr_t, deg_t, csr_pt, h2_ps, als2_pt, ald2_pt, b2_pt, t2, Nt);

    // ---- 8. output linears (bias fused) ----
    gemm_kernel<float><<<dim3(2, (Nt + 63) / 64), 256, 0, stream>>>(t2, Wo_t, out_t, bo_t, Nt, 128, 64);
    gemm_kernel<float><<<dim3(2, (Np + 63) / 64), 256, 0, stream>>>(p2, Wo_p, out_p, bo_p, Np, 128, 64);
}

// Round 5
// 1301.291 us; speedup vs baseline: 1.3295x; 1.3295x over previous
//
#include <hip/hip_runtime.h>

#define NEG_SLOPE 0.2f

typedef __attribute__((ext_vector_type(8))) short bf16x8;
typedef __attribute__((ext_vector_type(4))) float f32x4;

// ---------------- bf16 helpers ----------------
__device__ __forceinline__ float bf2f(unsigned short u) {
    return __uint_as_float(((unsigned int)u) << 16);
}
__device__ __forceinline__ unsigned short f2bf(float f) {
    unsigned int x = __float_as_uint(f);
    x += 0x7fffu + ((x >> 16) & 1u);  // round-to-nearest-even
    return (unsigned short)(x >> 16);
}
__device__ __forceinline__ float ld1(const float* p) { return *p; }
__device__ __forceinline__ float ld1(const unsigned short* p) { return bf2f(*p); }
__device__ __forceinline__ void st1(float* p, float v) { *p = v; }
__device__ __forceinline__ void st1(unsigned short* p, float v) { *p = f2bf(v); }

// ============================ convert / transpose ============================
__global__ void cvt_bf16_kernel(const float* __restrict__ in, unsigned short* __restrict__ out, int n) {
    int i = blockIdx.x * blockDim.x + threadIdx.x;
    if (i < n) out[i] = f2bf(in[i]);
}

// in [K,N] f32 row-major -> out [N,K] bf16 row-major
__global__ void transpose_cvt_kernel(const float* __restrict__ in, unsigned short* __restrict__ out,
                                     int K, int N) {
    int i = blockIdx.x * blockDim.x + threadIdx.x;
    if (i >= K * N) return;
    int k = i / N, n = i - k * N;
    out[(size_t)n * K + k] = f2bf(in[i]);
}

// ============================ fold kernels ============================
// layer1: out[d*8+h] = sum_c W[d,512][h*64+c] * av[h*64+c]
__global__ void fold1_kernel(const float* __restrict__ W, const float* __restrict__ av,
                             float* __restrict__ out) {
    int t = blockIdx.x * blockDim.x + threadIdx.x;
    if (t >= 128 * 8) return;
    int d = t >> 3, h = t & 7;
    const float* wr = W + d * 512 + h * 64;
    const float* ar = av + h * 64;
    float s = 0.f;
#pragma unroll
    for (int c = 0; c < 64; ++c) s = fmaf(wr[c], ar[c], s);
    out[t] = s;
}

// layer2 fold: out[d] = sum_c W[d*64+c]*av[c]   (W [512,64], av [64])
__global__ void fold2_kernel(const float* __restrict__ W, const float* __restrict__ av,
                             float* __restrict__ out) {
    int d = blockIdx.x * blockDim.x + threadIdx.x;
    if (d >= 512) return;
    const float* wr = W + d * 64;
    float s = 0.f;
#pragma unroll
    for (int c = 0; c < 64; ++c) s = fmaf(wr[c], av[c], s);
    out[d] = s;
}

// ============================ skinny projections ============================
// layer1: per node n (one wave): outA[n*8+h] = sum_d X[n,d]*wA[d*8+h]; same for B.
__global__ __launch_bounds__(256) void skinny1_kernel(
    const float* __restrict__ X, int N,
    const float* __restrict__ wA, const float* __restrict__ wB,
    float* __restrict__ outA, float* __restrict__ outB) {
    int w = (blockIdx.x * 256 + threadIdx.x) >> 6;
    int lane = threadIdx.x & 63;
    if (w >= N) return;
    float x0 = X[(size_t)w * 128 + lane];
    float x1 = X[(size_t)w * 128 + 64 + lane];
#pragma unroll
    for (int h = 0; h < 8; ++h) {
        float vA = x0 * wA[lane * 8 + h] + x1 * wA[(64 + lane) * 8 + h];
        float vB = x0 * wB[lane * 8 + h] + x1 * wB[(64 + lane) * 8 + h];
#pragma unroll
        for (int off = 32; off > 0; off >>= 1) {
            vA += __shfl_xor(vA, off);
            vB += __shfl_xor(vB, off);
        }
        if (lane == 0) { outA[(size_t)w * 8 + h] = vA; outB[(size_t)w * 8 + h] = vB; }
    }
}

// layer2: per node n (one wave): outA[n] = dot(X[n,:512], wa); outB[n] = dot(X[n,:512], wb)
template <typename XT>
__global__ __launch_bounds__(256) void skinny2_kernel(
    const XT* __restrict__ X, int N,
    const float* __restrict__ wa, const float* __restrict__ wb,
    float* __restrict__ outA, float* __restrict__ outB) {
    int w = (blockIdx.x * 256 + threadIdx.x) >> 6;
    int lane = threadIdx.x & 63;
    if (w >= N) return;
    float a = 0.f, b = 0.f;
#pragma unroll
    for (int i = 0; i < 8; ++i) {
        float x = ld1(X + (size_t)w * 512 + i * 64 + lane);
        a = fmaf(x, wa[i * 64 + lane], a);
        b = fmaf(x, wb[i * 64 + lane], b);
    }
#pragma unroll
    for (int off = 32; off > 0; off >>= 1) {
        a += __shfl_xor(a, off);
        b += __shfl_xor(b, off);
    }
    if (lane == 0) { outA[w] = a; outB[w] = b; }
}

// ============================ CSR build ============================
__global__ void hist_kernel(const int* __restrict__ dst, int E, int* __restrict__ deg) {
    int i = blockIdx.x * blockDim.x + threadIdx.x;
    if (i < E) atomicAdd(&deg[dst[i]], 1);
}

__global__ __launch_bounds__(512) void scan_chunk_kernel(const int* __restrict__ in, int N,
                                                         int* __restrict__ incl, int* __restrict__ sums) {
    __shared__ int sm[512];
    int i = blockIdx.x * 512 + threadIdx.x;
    int v = (i < N) ? in[i] : 0;
    sm[threadIdx.x] = v;
    __syncthreads();
    for (int off = 1; off < 512; off <<= 1) {
        int t = (threadIdx.x >= off) ? sm[threadIdx.x - off] : 0;
        __syncthreads();
        sm[threadIdx.x] += t;
        __syncthreads();
    }
    if (i < N) incl[i] = sm[threadIdx.x];
    if (threadIdx.x == 511) sums[blockIdx.x] = sm[511];
}

__global__ __launch_bounds__(512) void scan_sums_kernel(int* __restrict__ sums, int n) {
    __shared__ int sm[512];
    int v = (threadIdx.x < n) ? sums[threadIdx.x] : 0;
    sm[threadIdx.x] = v;
    __syncthreads();
    for (int off = 1; off < 512; off <<= 1) {
        int t = (threadIdx.x >= off) ? sm[threadIdx.x - off] : 0;
        __syncthreads();
        sm[threadIdx.x] += t;
        __syncthreads();
    }
    if (threadIdx.x < n) sums[threadIdx.x] = sm[threadIdx.x] - v;  // exclusive chunk offset
}

__global__ void scan_fin_kernel(const int* __restrict__ incl, const int* __restrict__ deg,
                                const int* __restrict__ sums, int N,
                                int* __restrict__ rowptr, int* __restrict__ cursor) {
    int i = blockIdx.x * blockDim.x + threadIdx.x;
    if (i >= N) return;
    int excl = incl[i] - deg[i] + sums[i >> 9];
    rowptr[i] = excl;
    cursor[i] = excl;
}

__global__ void scatter_kernel(const int* __restrict__ src, const int* __restrict__ dst, int E,
                               int* __restrict__ cursor, int* __restrict__ csr_src) {
    int i = blockIdx.x * blockDim.x + threadIdx.x;
    if (i >= E) return;
    int pos = atomicAdd(&cursor[dst[i]], 1);
    csr_src[pos] = src[i];
}

// ============================ aggregation (online softmax) ============================
// layer1: one BLOCK (8 waves) per dst; wave h = head h. 2-edge unrolled for MLP.
// hsrc [Nsrc,512] (HT); alsrc [Nsrc,8]; aldst [Ndst,8].
template <typename HT, typename OT>
__global__ __launch_bounds__(512) void agg1_kernel(
    const int* __restrict__ rowptr, const int* __restrict__ deg, const int* __restrict__ csr_src,
    const HT* __restrict__ hsrc, const float* __restrict__ alsrc, const float* __restrict__ aldst,
    const float* __restrict__ bias, OT* __restrict__ out, int Ndst) {
    int n = blockIdx.x;
    if (n >= Ndst) return;
    int h = threadIdx.x >> 6, lane = threadIdx.x & 63;
    int start = rowptr[n], cnt = deg[n];
    float ald = aldst[(size_t)n * 8 + h];
    float m = -INFINITY, s = 0.f, acc = 0.f;
    int i = 0;
    for (; i + 2 <= cnt; i += 2) {
        int sp0 = csr_src[start + i], sp1 = csr_src[start + i + 1];
        float e0 = alsrc[(size_t)sp0 * 8 + h] + ald;
        float e1 = alsrc[(size_t)sp1 * 8 + h] + ald;
        e0 = (e0 > 0.f) ? e0 : NEG_SLOPE * e0;
        e1 = (e1 > 0.f) ? e1 : NEG_SLOPE * e1;
        float hv0 = ld1(hsrc + (size_t)sp0 * 512 + h * 64 + lane);
        float hv1 = ld1(hsrc + (size_t)sp1 * 512 + h * 64 + lane);
        float mn = fmaxf(m, fmaxf(e0, e1));
        float sc = __expf(m - mn);
        float p0 = __expf(e0 - mn), p1 = __expf(e1 - mn);
        s = fmaf(s, sc, p0 + p1);
        acc = acc * sc;
        acc = fmaf(p0, hv0, acc);
        acc = fmaf(p1, hv1, acc);
        m = mn;
    }
    if (i < cnt) {
        int sp = csr_src[start + i];
        float e = alsrc[(size_t)sp * 8 + h] + ald;
        e = (e > 0.f) ? e : NEG_SLOPE * e;
        float hv = ld1(hsrc + (size_t)sp * 512 + h * 64 + lane);
        float mn = fmaxf(m, e);
        float sc = __expf(m - mn);
        float p = __expf(e - mn);
        s = fmaf(s, sc, p);
        acc = fmaf(p, hv, acc * sc);
    }
    float r = acc / (s + 1e-16f);
    float o = fmaxf(r + bias[h * 64 + lane], 0.f);
    st1(&out[(size_t)n * 512 + h * 64 + lane], o);
}

// layer2 (H=1,C=64): one wave per dst node, 2-edge unrolled. hsrc [Nsrc,64] (HT).
template <typename HT, typename OT>
__global__ __launch_bounds__(256) void agg2_kernel(
    const int* __restrict__ rowptr, const int* __restrict__ deg, const int* __restrict__ csr_src,
    const HT* __restrict__ hsrc, const float* __restrict__ alsrc, const float* __restrict__ aldst,
    const float* __restrict__ bias, OT* __restrict__ out, int Ndst) {
    int w = (blockIdx.x * 256 + threadIdx.x) >> 6;
    int lane = threadIdx.x & 63;
    if (w >= Ndst) return;
    int start = rowptr[w], cnt = deg[w];
    float ald = aldst[w];
    float m = -INFINITY, s = 0.f, acc = 0.f;
    int i = 0;
    for (; i + 2 <= cnt; i += 2) {
        int sp0 = csr_src[start + i], sp1 = csr_src[start + i + 1];
        float e0 = alsrc[sp0] + ald;
        float e1 = alsrc[sp1] + ald;
        e0 = (e0 > 0.f) ? e0 : NEG_SLOPE * e0;
        e1 = (e1 > 0.f) ? e1 : NEG_SLOPE * e1;
        float hv0 = ld1(hsrc + (size_t)sp0 * 64 + lane);
        float hv1 = ld1(hsrc + (size_t)sp1 * 64 + lane);
        float mn = fmaxf(m, fmaxf(e0, e1));
        float sc = __expf(m - mn);
        float p0 = __expf(e0 - mn), p1 = __expf(e1 - mn);
        s = fmaf(s, sc, p0 + p1);
        acc = acc * sc;
        acc = fmaf(p0, hv0, acc);
        acc = fmaf(p1, hv1, acc);
        m = mn;
    }
    if (i < cnt) {
        int sp = csr_src[start + i];
        float e = alsrc[sp] + ald;
        e = (e > 0.f) ? e : NEG_SLOPE * e;
        float hv = ld1(hsrc + (size_t)sp * 64 + lane);
        float mn = fmaxf(m, e);
        float sc = __expf(m - mn);
        float p = __expf(e - mn);
        s = fmaf(s, sc, p);
        acc = fmaf(p, hv, acc * sc);
    }
    st1(&out[(size_t)w * 64 + lane], fmaxf(acc / (s + 1e-16f) + bias[lane], 0.f));
}

// ============================ MFMA bf16 GEMM ============================
// C[M,N] = A[M,K](bf16) @ Bt[N,K](bf16, pre-transposed) [+bias]. fp32 accum.
// Block = 256 thr = 4 waves; wave w does rows [blk.x*64 + 16w, +16), cols [blk.y*NT*16, +NT*16).
// 16x16x32 frags: A lane l -> row l&15, k (l>>4)*8+j (16B contiguous).
//                 B lane l -> col l&15, k (l>>4)*8+j -> Bt[col][k...] 16B contiguous.
//                 C/D lane l -> col l&15, row (l>>4)*4+reg  [verified layout].
template <int NT, typename OT>
__global__ __launch_bounds__(256) void mfma_gemm_kernel(
    const unsigned short* __restrict__ A, const unsigned short* __restrict__ Bt,
    OT* __restrict__ C, const float* __restrict__ bias, int M, int N, int K) {
    int wave = threadIdx.x >> 6;
    int lane = threadIdx.x & 63;
    int m0 = blockIdx.x * 64 + wave * 16;
    int n0 = blockIdx.y * (NT * 16);
    int l15 = lane & 15;   // A-row within tile; C/B col within tile
    int kg = lane >> 4;    // 0..3
    f32x4 acc[NT];
#pragma unroll
    for (int t = 0; t < NT; ++t) acc[t] = (f32x4){0.f, 0.f, 0.f, 0.f};
    int arow = m0 + l15;
    const unsigned short* ap = A + (size_t)arow * K + kg * 8;
    const unsigned short* bp0 = Bt + (size_t)(n0 + l15) * K + kg * 8;
    for (int k0 = 0; k0 < K; k0 += 32) {
        bf16x8 af = {0, 0, 0, 0, 0, 0, 0, 0};
        if (arow < M) af = *(const bf16x8*)(ap + k0);
#pragma unroll
        for (int t = 0; t < NT; ++t) {
            bf16x8 bf_ = *(const bf16x8*)(bp0 + (size_t)t * 16 * K + k0);
            acc[t] = __builtin_amdgcn_mfma_f32_16x16x32_bf16(af, bf_, acc[t], 0, 0, 0);
        }
    }
    int orow0 = m0 + kg * 4;
#pragma unroll
    for (int t = 0; t < NT; ++t) {
        int ocol = n0 + t * 16 + l15;
        float bv = bias ? bias[ocol] : 0.f;
#pragma unroll
        for (int r = 0; r < 4; ++r) {
            int orow = orow0 + r;
            if (orow < M) st1(&C[(size_t)orow * N + ocol], acc[t][r] + bv);
        }
    }
}

// ============================ host launch ============================
static inline size_t align_up(size_t x, size_t a) { return (x + a - 1) / a * a; }

extern "C" void kernel_launch(void* const* d_in, const int* in_sizes, int n_in,
                              void* d_out, int out_size, void* d_ws, size_t ws_size,
                              hipStream_t stream) {
    const float* x_t = (const float*)d_in[0];
    const float* x_p = (const float*)d_in[1];
    const int* e_tp = (const int*)d_in[2];
    const int* e_pt = (const int*)d_in[3];
    const float* W1_tp = (const float*)d_in[4];
    const float* as1_tp = (const float*)d_in[5];
    const float* ad1_tp = (const float*)d_in[6];
    const float* b1_tp = (const float*)d_in[7];
    const float* W1_pt = (const float*)d_in[8];
    const float* as1_pt = (const float*)d_in[9];
    const float* ad1_pt = (const float*)d_in[10];
    const float* b1_pt = (const float*)d_in[11];
    const float* W2_tp = (const float*)d_in[12];
    const float* as2_tp = (const float*)d_in[13];
    const float* ad2_tp = (const float*)d_in[14];
    const float* b2_tp = (const float*)d_in[15];
    const float* W2_pt = (const float*)d_in[16];
    const float* as2_pt = (const float*)d_in[17];
    const float* ad2_pt = (const float*)d_in[18];
    const float* b2_pt = (const float*)d_in[19];
    const float* Wo_t = (const float*)d_in[20];
    const float* bo_t = (const float*)d_in[21];
    const float* Wo_p = (const float*)d_in[22];
    const float* bo_p = (const float*)d_in[23];

    const int Nt = in_sizes[0] / 128;
    const int Np = in_sizes[1] / 128;
    const int Etp = in_sizes[2] / 2;
    const int Ept = in_sizes[3] / 2;
    const size_t maxN = (Nt > Np) ? (size_t)Nt : (size_t)Np;

    // ---- workspace carve ----
    char* p = (char*)d_ws;
    auto alloc = [&](size_t bytes) -> void* {
        void* r = (void*)p;
        p += align_up(bytes, 256);
        return r;
    };
    float* als_tp = (float*)alloc((size_t)Nt * 8 * 4);
    float* ald_pt = (float*)alloc((size_t)Nt * 8 * 4);
    float* als_pt = (float*)alloc((size_t)Np * 8 * 4);
    float* ald_tp = (float*)alloc((size_t)Np * 8 * 4);
    float* als2_tp = (float*)alloc((size_t)Nt * 4);
    float* ald2_pt = (float*)alloc((size_t)Nt * 4);
    float* als2_pt = (float*)alloc((size_t)Np * 4);
    float* ald2_tp = (float*)alloc((size_t)Np * 4);
    float* was1_tp = (float*)alloc(128 * 8 * 4);
    float* wad1_tp = (float*)alloc(128 * 8 * 4);
    float* was1_pt = (float*)alloc(128 * 8 * 4);
    float* wad1_pt = (float*)alloc(128 * 8 * 4);
    float* was2_tp = (float*)alloc(512 * 4);
    float* wad2_tp = (float*)alloc(512 * 4);
    float* was2_pt = (float*)alloc(512 * 4);
    float* wad2_pt = (float*)alloc(512 * 4);
    int* deg_p = (int*)alloc((size_t)Np * 4);
    int* rowptr_p = (int*)alloc((size_t)Np * 4);
    int* cur_p = (int*)alloc((size_t)Np * 4);
    int* incl_p = (int*)alloc((size_t)Np * 4);
    int* deg_t = (int*)alloc((size_t)Nt * 4);
    int* rowptr_t = (int*)alloc((size_t)Nt * 4);
    int* cur_t = (int*)alloc((size_t)Nt * 4);
    int* incl_t = (int*)alloc((size_t)Nt * 4);
    int* csr_tp = (int*)alloc((size_t)Etp * 4);
    int* csr_pt = (int*)alloc((size_t)Ept * 4);
    int* sums_p = (int*)alloc(512 * 4);
    int* sums_t = (int*)alloc(512 * 4);
    // bf16 operands
    unsigned short* xbf_t = (unsigned short*)alloc((size_t)Nt * 128 * 2);
    unsigned short* xbf_p = (unsigned short*)alloc((size_t)Np * 128 * 2);
    unsigned short* Bt1_tp = (unsigned short*)alloc(512 * 128 * 2);
    unsigned short* Bt1_pt = (unsigned short*)alloc(512 * 128 * 2);
    unsigned short* Bt2_tp = (unsigned short*)alloc(64 * 512 * 2);
    unsigned short* Bt2_pt = (unsigned short*)alloc(64 * 512 * 2);
    unsigned short* Bto_t = (unsigned short*)alloc(128 * 64 * 2);
    unsigned short* Bto_p = (unsigned short*)alloc(128 * 64 * 2);
    // big shared h1/h2 buffer (bf16)
    unsigned short* H = (unsigned short*)alloc(maxN * 512 * 2);
    unsigned short* p1 = (unsigned short*)alloc((size_t)Np * 512 * 2);
    unsigned short* t1 = (unsigned short*)alloc((size_t)Nt * 512 * 2);
    // layer2 sub-buffers alias H (h1 values dead by then)
    unsigned short* h2_ts = H;                              // [Nt,64]
    unsigned short* h2_ps = H + (size_t)Nt * 64;            // [Np,64]
    unsigned short* p2 = h2_ps + (size_t)Np * 64;           // [Np,64]
    unsigned short* t2 = p2 + (size_t)Np * 64;              // [Nt,64]

    if ((size_t)(p - (char*)d_ws) > ws_size) return;  // clean-fail diagnostic

    float* out_t = (float*)d_out;
    float* out_p = (float*)d_out + (size_t)Nt * 128;

    // ---- 0. zero degree arrays ----
    hipMemsetAsync(deg_p, 0, (size_t)Np * 4, stream);
    hipMemsetAsync(deg_t, 0, (size_t)Nt * 4, stream);

    // ---- 1. folds + layer1 skinny projections + bf16 conversions ----
    fold1_kernel<<<4, 256, 0, stream>>>(W1_tp, as1_tp, was1_tp);
    fold1_kernel<<<4, 256, 0, stream>>>(W1_tp, ad1_tp, wad1_tp);
    fold1_kernel<<<4, 256, 0, stream>>>(W1_pt, as1_pt, was1_pt);
    fold1_kernel<<<4, 256, 0, stream>>>(W1_pt, ad1_pt, wad1_pt);
    fold2_kernel<<<2, 256, 0, stream>>>(W2_tp, as2_tp, was2_tp);
    fold2_kernel<<<2, 256, 0, stream>>>(W2_tp, ad2_tp, wad2_tp);
    fold2_kernel<<<2, 256, 0, stream>>>(W2_pt, as2_pt, was2_pt);
    fold2_kernel<<<2, 256, 0, stream>>>(W2_pt, ad2_pt, wad2_pt);
    skinny1_kernel<<<(Nt + 3) / 4, 256, 0, stream>>>(x_t, Nt, was1_tp, wad1_pt, als_tp, ald_pt);
    skinny1_kernel<<<(Np + 3) / 4, 256, 0, stream>>>(x_p, Np, was1_pt, wad1_tp, als_pt, ald_tp);
    cvt_bf16_kernel<<<(Nt * 128 + 255) / 256, 256, 0, stream>>>(x_t, xbf_t, Nt * 128);
    cvt_bf16_kernel<<<(Np * 128 + 255) / 256, 256, 0, stream>>>(x_p, xbf_p, Np * 128);
    transpose_cvt_kernel<<<(128 * 512 + 255) / 256, 256, 0, stream>>>(W1_tp, Bt1_tp, 128, 512);
    transpose_cvt_kernel<<<(128 * 512 + 255) / 256, 256, 0, stream>>>(W1_pt, Bt1_pt, 128, 512);
    transpose_cvt_kernel<<<(512 * 64 + 255) / 256, 256, 0, stream>>>(W2_tp, Bt2_tp, 512, 64);
    transpose_cvt_kernel<<<(512 * 64 + 255) / 256, 256, 0, stream>>>(W2_pt, Bt2_pt, 512, 64);
    transpose_cvt_kernel<<<(64 * 128 + 255) / 256, 256, 0, stream>>>(Wo_t, Bto_t, 64, 128);
    transpose_cvt_kernel<<<(64 * 128 + 255) / 256, 256, 0, stream>>>(Wo_p, Bto_p, 64, 128);

    // ---- 2. CSR build (dst-sorted), reused by both layers ----
    hist_kernel<<<(Etp + 255) / 256, 256, 0, stream>>>(e_tp + Etp, Etp, deg_p);
    hist_kernel<<<(Ept + 255) / 256, 256, 0, stream>>>(e_pt + Ept, Ept, deg_t);
    int nchp = (Np + 511) / 512, ncht = (Nt + 511) / 512;
    scan_chunk_kernel<<<nchp, 512, 0, stream>>>(deg_p, Np, incl_p, sums_p);
    scan_sums_kernel<<<1, 512, 0, stream>>>(sums_p, nchp);
    scan_fin_kernel<<<(Np + 255) / 256, 256, 0, stream>>>(incl_p, deg_p, sums_p, Np, rowptr_p, cur_p);
    scan_chunk_kernel<<<ncht, 512, 0, stream>>>(deg_t, Nt, incl_t, sums_t);
    scan_sums_kernel<<<1, 512, 0, stream>>>(sums_t, ncht);
    scan_fin_kernel<<<(Nt + 255) / 256, 256, 0, stream>>>(incl_t, deg_t, sums_t, Nt, rowptr_t, cur_t);
    scatter_kernel<<<(Etp + 255) / 256, 256, 0, stream>>>(e_tp, e_tp + Etp, Etp, cur_p, csr_tp);
    scatter_kernel<<<(Ept + 255) / 256, 256, 0, stream>>>(e_pt, e_pt + Ept, Ept, cur_t, csr_pt);

    // ---- 3. layer1: h1_ts -> agg(p); h1_ps -> agg(t)  (H reused) ----
    mfma_gemm_kernel<8, unsigned short><<<dim3((Nt + 63) / 64, 4), 256, 0, stream>>>(
        xbf_t, Bt1_tp, H, nullptr, Nt, 512, 128);
    agg1_kernel<unsigned short, unsigned short><<<Np, 512, 0, stream>>>(
        rowptr_p, deg_p, csr_tp, H, als_tp, ald_tp, b1_tp, p1, Np);
    mfma_gemm_kernel<8, unsigned short><<<dim3((Np + 63) / 64, 4), 256, 0, stream>>>(
        xbf_p, Bt1_pt, H, nullptr, Np, 512, 128);
    agg1_kernel<unsigned short, unsigned short><<<Nt, 512, 0, stream>>>(
        rowptr_t, deg_t, csr_pt, H, als_pt, ald_pt, b1_pt, t1, Nt);

    // ---- 4. layer2 skinny projections ----
    skinny2_kernel<unsigned short><<<(Nt + 3) / 4, 256, 0, stream>>>(t1, Nt, was2_tp, wad2_pt, als2_tp, ald2_pt);
    skinny2_kernel<unsigned short><<<(Np + 3) / 4, 256, 0, stream>>>(p1, Np, was2_pt, wad2_tp, als2_pt, ald2_tp);

    // ---- 5. layer2 GEMMs (into H head; h1 dead) ----
    mfma_gemm_kernel<4, unsigned short><<<dim3((Nt + 63) / 64, 1), 256, 0, stream>>>(
        t1, Bt2_tp, h2_ts, nullptr, Nt, 64, 512);
    mfma_gemm_kernel<4, unsigned short><<<dim3((Np + 63) / 64, 1), 256, 0, stream>>>(
        p1, Bt2_pt, h2_ps, nullptr, Np, 64, 512);

    // ---- 6. layer2 aggregation (bias+relu fused) ----
    agg2_kernel<unsigned short, unsigned short><<<(Np + 3) / 4, 256, 0, stream>>>(
        rowptr_p, deg_p, csr_tp, h2_ts, als2_tp, ald2_tp, b2_tp, p2, Np);
    agg2_kernel<unsigned short, unsigned short><<<(Nt + 3) / 4, 256, 0, stream>>>(
        rowptr_t, deg_t, csr_pt, h2_ps, als2_pt, ald2_pt, b2_pt, t2, Nt);

    // ---- 7. output linears (bias fused, f32 out) ----
    mfma_gemm_kernel<8, float><<<dim3((Nt + 63) / 64, 1), 256, 0, stream>>>(
        t2, Bto_t, out_t, bo_t, Nt, 128, 64);
    mfma_gemm_kernel<8, float><<<dim3((Np + 63) / 64, 1), 256, 0, stream>>>(
        p2, Bto_p, out_p, bo_p, Np, 128, 64);
}

// Round 6
// 976.270 us; speedup vs baseline: 1.7721x; 1.3329x over previous
//
#include <hip/hip_runtime.h>

#define NEG_SLOPE 0.2f

typedef __attribute__((ext_vector_type(8))) short bf16x8;
typedef __attribute__((ext_vector_type(4))) float f32x4;

// ---------------- bf16 helpers ----------------
__device__ __forceinline__ float bf2f(unsigned short u) {
    return __uint_as_float(((unsigned int)u) << 16);
}
__device__ __forceinline__ unsigned short f2bf(float f) {
    unsigned int x = __float_as_uint(f);
    x += 0x7fffu + ((x >> 16) & 1u);  // round-to-nearest-even
    return (unsigned short)(x >> 16);
}
__device__ __forceinline__ float ld1(const float* p) { return *p; }
__device__ __forceinline__ float ld1(const unsigned short* p) { return bf2f(*p); }
__device__ __forceinline__ void st1(float* p, float v) { *p = v; }
__device__ __forceinline__ void st1(unsigned short* p, float v) { *p = f2bf(v); }

// ============================ convert / transpose ============================
__global__ void cvt_bf16_kernel(const float* __restrict__ in, unsigned short* __restrict__ out, int n) {
    int i = blockIdx.x * blockDim.x + threadIdx.x;
    if (i < n) out[i] = f2bf(in[i]);
}

// in [K,N] f32 row-major -> out [N,K] bf16 row-major
__global__ void transpose_cvt_kernel(const float* __restrict__ in, unsigned short* __restrict__ out,
                                     int K, int N) {
    int i = blockIdx.x * blockDim.x + threadIdx.x;
    if (i >= K * N) return;
    int k = i / N, n = i - k * N;
    out[(size_t)n * K + k] = f2bf(in[i]);
}

// ============================ attention-weight folds (direct to bf16 Bt) ============================
// layer1 al Bt [16,128]: row h<8: (W_s[128,512]·av_s)[h]; row h>=8: (W_d·av_d)[h-8]
__global__ void fold1_bt_kernel(const float* __restrict__ W_s, const float* __restrict__ av_s,
                                const float* __restrict__ W_d, const float* __restrict__ av_d,
                                unsigned short* __restrict__ out) {
    int idx = blockIdx.x * blockDim.x + threadIdx.x;
    if (idx >= 16 * 128) return;
    int h = idx >> 7, d = idx & 127;
    const float* W = (h < 8) ? W_s : W_d;
    const float* a = (h < 8) ? (av_s + h * 64) : (av_d + (h - 8) * 64);
    const float* wr = W + (size_t)d * 512 + (h & 7) * 64;
    float s = 0.f;
#pragma unroll
    for (int c = 0; c < 64; ++c) s = fmaf(wr[c], a[c], s);
    out[idx] = f2bf(s);
}

// layer2 al Bt [16,512]: row0: W_s[512,64]·av_s ; row1: W_d·av_d ; rows 2-15 zero
__global__ void fold2_bt_kernel(const float* __restrict__ W_s, const float* __restrict__ av_s,
                                const float* __restrict__ W_d, const float* __restrict__ av_d,
                                unsigned short* __restrict__ out) {
    int idx = blockIdx.x * blockDim.x + threadIdx.x;
    if (idx >= 16 * 512) return;
    int h = idx >> 9, d = idx & 511;
    float s = 0.f;
    if (h < 2) {
        const float* W = (h == 0) ? W_s : W_d;
        const float* a = (h == 0) ? av_s : av_d;
        const float* wr = W + (size_t)d * 64;
#pragma unroll
        for (int c = 0; c < 64; ++c) s = fmaf(wr[c], a[c], s);
    }
    out[idx] = f2bf(s);
}

// ============================ CSR build ============================
__global__ void hist_kernel(const int* __restrict__ dst, int E, int* __restrict__ deg) {
    int i = blockIdx.x * blockDim.x + threadIdx.x;
    if (i < E) atomicAdd(&deg[dst[i]], 1);
}

__global__ __launch_bounds__(512) void scan_chunk_kernel(const int* __restrict__ in, int N,
                                                         int* __restrict__ incl, int* __restrict__ sums) {
    __shared__ int sm[512];
    int i = blockIdx.x * 512 + threadIdx.x;
    int v = (i < N) ? in[i] : 0;
    sm[threadIdx.x] = v;
    __syncthreads();
    for (int off = 1; off < 512; off <<= 1) {
        int t = (threadIdx.x >= off) ? sm[threadIdx.x - off] : 0;
        __syncthreads();
        sm[threadIdx.x] += t;
        __syncthreads();
    }
    if (i < N) incl[i] = sm[threadIdx.x];
    if (threadIdx.x == 511) sums[blockIdx.x] = sm[511];
}

__global__ __launch_bounds__(512) void scan_sums_kernel(int* __restrict__ sums, int n) {
    __shared__ int sm[512];
    int v = (threadIdx.x < n) ? sums[threadIdx.x] : 0;
    sm[threadIdx.x] = v;
    __syncthreads();
    for (int off = 1; off < 512; off <<= 1) {
        int t = (threadIdx.x >= off) ? sm[threadIdx.x - off] : 0;
        __syncthreads();
        sm[threadIdx.x] += t;
        __syncthreads();
    }
    if (threadIdx.x < n) sums[threadIdx.x] = sm[threadIdx.x] - v;  // exclusive chunk offset
}

__global__ void scan_fin_kernel(const int* __restrict__ incl, const int* __restrict__ deg,
                                const int* __restrict__ sums, int N,
                                int* __restrict__ rowptr, int* __restrict__ cursor) {
    int i = blockIdx.x * blockDim.x + threadIdx.x;
    if (i >= N) return;
    int excl = incl[i] - deg[i] + sums[i >> 9];
    rowptr[i] = excl;
    cursor[i] = excl;
}

__global__ void scatter_kernel(const int* __restrict__ src, const int* __restrict__ dst, int E,
                               int* __restrict__ cursor, int* __restrict__ csr_src) {
    int i = blockIdx.x * blockDim.x + threadIdx.x;
    if (i >= E) return;
    int pos = atomicAdd(&cursor[dst[i]], 1);
    csr_src[pos] = src[i];
}

// ============================ aggregation (online softmax) ============================
// layer1: one BLOCK (8 waves) per dst; wave h = head h. 2-edge unrolled for MLP.
// hsrc [Nsrc,512]; alsrc [Nsrc,16] (cols 0-7 = src-att); aldst [Ndst,16] (cols 8-15 = dst-att).
template <typename HT, typename OT>
__global__ __launch_bounds__(512) void agg1_kernel(
    const int* __restrict__ rowptr, const int* __restrict__ deg, const int* __restrict__ csr_src,
    const HT* __restrict__ hsrc, const float* __restrict__ alsrc, const float* __restrict__ aldst,
    const float* __restrict__ bias, OT* __restrict__ out, int Ndst) {
    int n = blockIdx.x;
    if (n >= Ndst) return;
    int h = threadIdx.x >> 6, lane = threadIdx.x & 63;
    int start = rowptr[n], cnt = deg[n];
    float ald = aldst[(size_t)n * 16 + 8 + h];
    float m = -INFINITY, s = 0.f, acc = 0.f;
    int i = 0;
    for (; i + 2 <= cnt; i += 2) {
        int sp0 = csr_src[start + i], sp1 = csr_src[start + i + 1];
        float e0 = alsrc[(size_t)sp0 * 16 + h] + ald;
        float e1 = alsrc[(size_t)sp1 * 16 + h] + ald;
        e0 = (e0 > 0.f) ? e0 : NEG_SLOPE * e0;
        e1 = (e1 > 0.f) ? e1 : NEG_SLOPE * e1;
        float hv0 = ld1(hsrc + (size_t)sp0 * 512 + h * 64 + lane);
        float hv1 = ld1(hsrc + (size_t)sp1 * 512 + h * 64 + lane);
        float mn = fmaxf(m, fmaxf(e0, e1));
        float sc = __expf(m - mn);
        float p0 = __expf(e0 - mn), p1 = __expf(e1 - mn);
        s = fmaf(s, sc, p0 + p1);
        acc = acc * sc;
        acc = fmaf(p0, hv0, acc);
        acc = fmaf(p1, hv1, acc);
        m = mn;
    }
    if (i < cnt) {
        int sp = csr_src[start + i];
        float e = alsrc[(size_t)sp * 16 + h] + ald;
        e = (e > 0.f) ? e : NEG_SLOPE * e;
        float hv = ld1(hsrc + (size_t)sp * 512 + h * 64 + lane);
        float mn = fmaxf(m, e);
        float sc = __expf(m - mn);
        float p = __expf(e - mn);
        s = fmaf(s, sc, p);
        acc = fmaf(p, hv, acc * sc);
    }
    float r = acc / (s + 1e-16f);
    float o = fmaxf(r + bias[h * 64 + lane], 0.f);
    st1(&out[(size_t)n * 512 + h * 64 + lane], o);
}

// layer2 (H=1,C=64): one wave per dst node, 2-edge unrolled.
// hsrc [Nsrc,64]; alsrc [Nsrc,16] col 0; aldst [Ndst,16] col 1.
template <typename HT, typename OT>
__global__ __launch_bounds__(256) void agg2_kernel(
    const int* __restrict__ rowptr, const int* __restrict__ deg, const int* __restrict__ csr_src,
    const HT* __restrict__ hsrc, const float* __restrict__ alsrc, const float* __restrict__ aldst,
    const float* __restrict__ bias, OT* __restrict__ out, int Ndst) {
    int w = (blockIdx.x * 256 + threadIdx.x) >> 6;
    int lane = threadIdx.x & 63;
    if (w >= Ndst) return;
    int start = rowptr[w], cnt = deg[w];
    float ald = aldst[(size_t)w * 16 + 1];
    float m = -INFINITY, s = 0.f, acc = 0.f;
    int i = 0;
    for (; i + 2 <= cnt; i += 2) {
        int sp0 = csr_src[start + i], sp1 = csr_src[start + i + 1];
        float e0 = alsrc[(size_t)sp0 * 16] + ald;
        float e1 = alsrc[(size_t)sp1 * 16] + ald;
        e0 = (e0 > 0.f) ? e0 : NEG_SLOPE * e0;
        e1 = (e1 > 0.f) ? e1 : NEG_SLOPE * e1;
        float hv0 = ld1(hsrc + (size_t)sp0 * 64 + lane);
        float hv1 = ld1(hsrc + (size_t)sp1 * 64 + lane);
        float mn = fmaxf(m, fmaxf(e0, e1));
        float sc = __expf(m - mn);
        float p0 = __expf(e0 - mn), p1 = __expf(e1 - mn);
        s = fmaf(s, sc, p0 + p1);
        acc = acc * sc;
        acc = fmaf(p0, hv0, acc);
        acc = fmaf(p1, hv1, acc);
        m = mn;
    }
    if (i < cnt) {
        int sp = csr_src[start + i];
        float e = alsrc[(size_t)sp * 16] + ald;
        e = (e > 0.f) ? e : NEG_SLOPE * e;
        float hv = ld1(hsrc + (size_t)sp * 64 + lane);
        float mn = fmaxf(m, e);
        float sc = __expf(m - mn);
        float p = __expf(e - mn);
        s = fmaf(s, sc, p);
        acc = fmaf(p, hv, acc * sc);
    }
    st1(&out[(size_t)w * 64 + lane], fmaxf(acc / (s + 1e-16f) + bias[lane], 0.f));
}

// ============================ MFMA bf16 GEMM ============================
// C[M,N] = A[M,K](bf16) @ Bt[N,K](bf16, pre-transposed) [+bias]. fp32 accum.
// Block = 256 thr = 4 waves; wave w does rows [blk.x*64 + 16w, +16), cols [blk.y*NT*16, +NT*16).
template <int NT, typename OT>
__global__ __launch_bounds__(256) void mfma_gemm_kernel(
    const unsigned short* __restrict__ A, const unsigned short* __restrict__ Bt,
    OT* __restrict__ C, const float* __restrict__ bias, int M, int N, int K) {
    int wave = threadIdx.x >> 6;
    int lane = threadIdx.x & 63;
    int m0 = blockIdx.x * 64 + wave * 16;
    int n0 = blockIdx.y * (NT * 16);
    int l15 = lane & 15;   // A-row within tile; C/B col within tile
    int kg = lane >> 4;    // 0..3
    f32x4 acc[NT];
#pragma unroll
    for (int t = 0; t < NT; ++t) acc[t] = (f32x4){0.f, 0.f, 0.f, 0.f};
    int arow = m0 + l15;
    const unsigned short* ap = A + (size_t)arow * K + kg * 8;
    const unsigned short* bp0 = Bt + (size_t)(n0 + l15) * K + kg * 8;
    for (int k0 = 0; k0 < K; k0 += 32) {
        bf16x8 af = {0, 0, 0, 0, 0, 0, 0, 0};
        if (arow < M) af = *(const bf16x8*)(ap + k0);
#pragma unroll
        for (int t = 0; t < NT; ++t) {
            bf16x8 bf_ = *(const bf16x8*)(bp0 + (size_t)t * 16 * K + k0);
            acc[t] = __builtin_amdgcn_mfma_f32_16x16x32_bf16(af, bf_, acc[t], 0, 0, 0);
        }
    }
    int orow0 = m0 + kg * 4;
#pragma unroll
    for (int t = 0; t < NT; ++t) {
        int ocol = n0 + t * 16 + l15;
        float bv = bias ? bias[ocol] : 0.f;
#pragma unroll
        for (int r = 0; r < 4; ++r) {
            int orow = orow0 + r;
            if (orow < M) st1(&C[(size_t)orow * N + ocol], acc[t][r] + bv);
        }
    }
}

// ============================ host launch ============================
static inline size_t align_up(size_t x, size_t a) { return (x + a - 1) / a * a; }

extern "C" void kernel_launch(void* const* d_in, const int* in_sizes, int n_in,
                              void* d_out, int out_size, void* d_ws, size_t ws_size,
                              hipStream_t stream) {
    const float* x_t = (const float*)d_in[0];
    const float* x_p = (const float*)d_in[1];
    const int* e_tp = (const int*)d_in[2];
    const int* e_pt = (const int*)d_in[3];
    const float* W1_tp = (const float*)d_in[4];
    const float* as1_tp = (const float*)d_in[5];
    const float* ad1_tp = (const float*)d_in[6];
    const float* b1_tp = (const float*)d_in[7];
    const float* W1_pt = (const float*)d_in[8];
    const float* as1_pt = (const float*)d_in[9];
    const float* ad1_pt = (const float*)d_in[10];
    const float* b1_pt = (const float*)d_in[11];
    const float* W2_tp = (const float*)d_in[12];
    const float* as2_tp = (const float*)d_in[13];
    const float* ad2_tp = (const float*)d_in[14];
    const float* b2_tp = (const float*)d_in[15];
    const float* W2_pt = (const float*)d_in[16];
    const float* as2_pt = (const float*)d_in[17];
    const float* ad2_pt = (const float*)d_in[18];
    const float* b2_pt = (const float*)d_in[19];
    const float* Wo_t = (const float*)d_in[20];
    const float* bo_t = (const float*)d_in[21];
    const float* Wo_p = (const float*)d_in[22];
    const float* bo_p = (const float*)d_in[23];

    const int Nt = in_sizes[0] / 128;
    const int Np = in_sizes[1] / 128;
    const int Etp = in_sizes[2] / 2;
    const int Ept = in_sizes[3] / 2;
    const size_t maxN = (Nt > Np) ? (size_t)Nt : (size_t)Np;

    // ---- workspace carve ----
    char* p = (char*)d_ws;
    auto alloc = [&](size_t bytes) -> void* {
        void* r = (void*)p;
        p += align_up(bytes, 256);
        return r;
    };
    // packed al arrays [N,16] f32
    float* al_t = (float*)alloc((size_t)Nt * 16 * 4);
    float* al_p = (float*)alloc((size_t)Np * 16 * 4);
    float* al2_t = (float*)alloc((size_t)Nt * 16 * 4);
    float* al2_p = (float*)alloc((size_t)Np * 16 * 4);
    // folded al weight Bt's (bf16)
    unsigned short* albt_t = (unsigned short*)alloc(16 * 128 * 2);
    unsigned short* albt_p = (unsigned short*)alloc(16 * 128 * 2);
    unsigned short* albt2_t = (unsigned short*)alloc(16 * 512 * 2);
    unsigned short* albt2_p = (unsigned short*)alloc(16 * 512 * 2);
    int* deg_p = (int*)alloc((size_t)Np * 4);
    int* rowptr_p = (int*)alloc((size_t)Np * 4);
    int* cur_p = (int*)alloc((size_t)Np * 4);
    int* incl_p = (int*)alloc((size_t)Np * 4);
    int* deg_t = (int*)alloc((size_t)Nt * 4);
    int* rowptr_t = (int*)alloc((size_t)Nt * 4);
    int* cur_t = (int*)alloc((size_t)Nt * 4);
    int* incl_t = (int*)alloc((size_t)Nt * 4);
    int* csr_tp = (int*)alloc((size_t)Etp * 4);
    int* csr_pt = (int*)alloc((size_t)Ept * 4);
    int* sums_p = (int*)alloc(512 * 4);
    int* sums_t = (int*)alloc(512 * 4);
    // bf16 operands
    unsigned short* xbf_t = (unsigned short*)alloc((size_t)Nt * 128 * 2);
    unsigned short* xbf_p = (unsigned short*)alloc((size_t)Np * 128 * 2);
    unsigned short* Bt1_tp = (unsigned short*)alloc(512 * 128 * 2);
    unsigned short* Bt1_pt = (unsigned short*)alloc(512 * 128 * 2);
    unsigned short* Bt2_tp = (unsigned short*)alloc(64 * 512 * 2);
    unsigned short* Bt2_pt = (unsigned short*)alloc(64 * 512 * 2);
    unsigned short* Bto_t = (unsigned short*)alloc(128 * 64 * 2);
    unsigned short* Bto_p = (unsigned short*)alloc(128 * 64 * 2);
    // big shared h1/h2 buffer (bf16)
    unsigned short* H = (unsigned short*)alloc(maxN * 512 * 2);
    unsigned short* p1 = (unsigned short*)alloc((size_t)Np * 512 * 2);
    unsigned short* t1 = (unsigned short*)alloc((size_t)Nt * 512 * 2);
    // layer2 sub-buffers alias H (h1 values dead by then)
    unsigned short* h2_ts = H;                              // [Nt,64]
    unsigned short* h2_ps = H + (size_t)Nt * 64;            // [Np,64]
    unsigned short* p2 = h2_ps + (size_t)Np * 64;           // [Np,64]
    unsigned short* t2 = p2 + (size_t)Np * 64;              // [Nt,64]

    if ((size_t)(p - (char*)d_ws) > ws_size) return;  // clean-fail diagnostic

    float* out_t = (float*)d_out;
    float* out_p = (float*)d_out + (size_t)Nt * 128;

    // ---- 0. zero degree arrays ----
    hipMemsetAsync(deg_p, 0, (size_t)Np * 4, stream);
    hipMemsetAsync(deg_t, 0, (size_t)Nt * 4, stream);

    // ---- 1. folds + bf16 conversions ----
    fold1_bt_kernel<<<8, 256, 0, stream>>>(W1_tp, as1_tp, W1_pt, ad1_pt, albt_t);
    fold1_bt_kernel<<<8, 256, 0, stream>>>(W1_pt, as1_pt, W1_tp, ad1_tp, albt_p);
    fold2_bt_kernel<<<32, 256, 0, stream>>>(W2_tp, as2_tp, W2_pt, ad2_pt, albt2_t);
    fold2_bt_kernel<<<32, 256, 0, stream>>>(W2_pt, as2_pt, W2_tp, ad2_tp, albt2_p);
    cvt_bf16_kernel<<<(Nt * 128 + 255) / 256, 256, 0, stream>>>(x_t, xbf_t, Nt * 128);
    cvt_bf16_kernel<<<(Np * 128 + 255) / 256, 256, 0, stream>>>(x_p, xbf_p, Np * 128);
    transpose_cvt_kernel<<<(128 * 512 + 255) / 256, 256, 0, stream>>>(W1_tp, Bt1_tp, 128, 512);
    transpose_cvt_kernel<<<(128 * 512 + 255) / 256, 256, 0, stream>>>(W1_pt, Bt1_pt, 128, 512);
    transpose_cvt_kernel<<<(512 * 64 + 255) / 256, 256, 0, stream>>>(W2_tp, Bt2_tp, 512, 64);
    transpose_cvt_kernel<<<(512 * 64 + 255) / 256, 256, 0, stream>>>(W2_pt, Bt2_pt, 512, 64);
    transpose_cvt_kernel<<<(64 * 128 + 255) / 256, 256, 0, stream>>>(Wo_t, Bto_t, 64, 128);
    transpose_cvt_kernel<<<(64 * 128 + 255) / 256, 256, 0, stream>>>(Wo_p, Bto_p, 64, 128);

    // ---- 2. al1 projections via MFMA: [N,128]@[128,16] ----
    mfma_gemm_kernel<1, float><<<dim3((Nt + 63) / 64, 1), 256, 0, stream>>>(
        xbf_t, albt_t, al_t, nullptr, Nt, 16, 128);
    mfma_gemm_kernel<1, float><<<dim3((Np + 63) / 64, 1), 256, 0, stream>>>(
        xbf_p, albt_p, al_p, nullptr, Np, 16, 128);

    // ---- 3. CSR build (dst-sorted), reused by both layers ----
    hist_kernel<<<(Etp + 255) / 256, 256, 0, stream>>>(e_tp + Etp, Etp, deg_p);
    hist_kernel<<<(Ept + 255) / 256, 256, 0, stream>>>(e_pt + Ept, Ept, deg_t);
    int nchp = (Np + 511) / 512, ncht = (Nt + 511) / 512;
    scan_chunk_kernel<<<nchp, 512, 0, stream>>>(deg_p, Np, incl_p, sums_p);
    scan_sums_kernel<<<1, 512, 0, stream>>>(sums_p, nchp);
    scan_fin_kernel<<<(Np + 255) / 256, 256, 0, stream>>>(incl_p, deg_p, sums_p, Np, rowptr_p, cur_p);
    scan_chunk_kernel<<<ncht, 512, 0, stream>>>(deg_t, Nt, incl_t, sums_t);
    scan_sums_kernel<<<1, 512, 0, stream>>>(sums_t, ncht);
    scan_fin_kernel<<<(Nt + 255) / 256, 256, 0, stream>>>(incl_t, deg_t, sums_t, Nt, rowptr_t, cur_t);
    scatter_kernel<<<(Etp + 255) / 256, 256, 0, stream>>>(e_tp, e_tp + Etp, Etp, cur_p, csr_tp);
    scatter_kernel<<<(Ept + 255) / 256, 256, 0, stream>>>(e_pt, e_pt + Ept, Ept, cur_t, csr_pt);

    // ---- 4. layer1: h1_ts -> agg(p); h1_ps -> agg(t)  (H reused) ----
    mfma_gemm_kernel<8, unsigned short><<<dim3((Nt + 63) / 64, 4), 256, 0, stream>>>(
        xbf_t, Bt1_tp, H, nullptr, Nt, 512, 128);
    agg1_kernel<unsigned short, unsigned short><<<Np, 512, 0, stream>>>(
        rowptr_p, deg_p, csr_tp, H, al_t, al_p, b1_tp, p1, Np);
    mfma_gemm_kernel<8, unsigned short><<<dim3((Np + 63) / 64, 4), 256, 0, stream>>>(
        xbf_p, Bt1_pt, H, nullptr, Np, 512, 128);
    agg1_kernel<unsigned short, unsigned short><<<Nt, 512, 0, stream>>>(
        rowptr_t, deg_t, csr_pt, H, al_p, al_t, b1_pt, t1, Nt);

    // ---- 5. al2 projections via MFMA: [N,512]@[512,16] ----
    mfma_gemm_kernel<1, float><<<dim3((Nt + 63) / 64, 1), 256, 0, stream>>>(
        t1, albt2_t, al2_t, nullptr, Nt, 16, 512);
    mfma_gemm_kernel<1, float><<<dim3((Np + 63) / 64, 1), 256, 0, stream>>>(
        p1, albt2_p, al2_p, nullptr, Np, 16, 512);

    // ---- 6. layer2 GEMMs (into H head; h1 dead) ----
    mfma_gemm_kernel<4, unsigned short><<<dim3((Nt + 63) / 64, 1), 256, 0, stream>>>(
        t1, Bt2_tp, h2_ts, nullptr, Nt, 64, 512);
    mfma_gemm_kernel<4, unsigned short><<<dim3((Np + 63) / 64, 1), 256, 0, stream>>>(
        p1, Bt2_pt, h2_ps, nullptr, Np, 64, 512);

    // ---- 7. layer2 aggregation (bias+relu fused) ----
    agg2_kernel<unsigned short, unsigned short><<<(Np + 3) / 4, 256, 0, stream>>>(
        rowptr_p, deg_p, csr_tp, h2_ts, al2_t, al2_p, b2_tp, p2, Np);
    agg2_kernel<unsigned short, unsigned short><<<(Nt + 3) / 4, 256, 0, stream>>>(
        rowptr_t, deg_t, csr_pt, h2_ps, al2_p, al2_t, b2_pt, t2, Nt);

    // ---- 8. output linears (bias fused, f32 out) ----
    mfma_gemm_kernel<8, float><<<dim3((Nt + 63) / 64, 1), 256, 0, stream>>>(
        t2, Bto_t, out_t, bo_t, Nt, 128, 64);
    mfma_gemm_kernel<8, float><<<dim3((Np + 63) / 64, 1), 256, 0, stream>>>(
        p2, Bto_p, out_p, bo_p, Np, 128, 64);
}

// Round 7
// 950.368 us; speedup vs baseline: 1.8204x; 1.0273x over previous
//
#include <hip/hip_runtime.h>

#define NEG_SLOPE 0.2f

typedef __attribute__((ext_vector_type(8))) short bf16x8;
typedef __attribute__((ext_vector_type(4))) float f32x4;

// ---------------- bf16 helpers ----------------
__device__ __forceinline__ float bf2f(unsigned short u) {
    return __uint_as_float(((unsigned int)u) << 16);
}
__device__ __forceinline__ unsigned short f2bf(float f) {
    unsigned int x = __float_as_uint(f);
    x += 0x7fffu + ((x >> 16) & 1u);  // round-to-nearest-even
    return (unsigned short)(x >> 16);
}
__device__ __forceinline__ float ld1(const float* p) { return *p; }
__device__ __forceinline__ float ld1(const unsigned short* p) { return bf2f(*p); }
__device__ __forceinline__ void st1(float* p, float v) { *p = v; }
__device__ __forceinline__ void st1(unsigned short* p, float v) { *p = f2bf(v); }

// ============================ convert / transpose ============================
__global__ void cvt_bf16_kernel(const float* __restrict__ in, unsigned short* __restrict__ out, int n) {
    int i = blockIdx.x * blockDim.x + threadIdx.x;
    if (i < n) out[i] = f2bf(in[i]);
}

// in [K,N] f32 row-major -> out [N,K] bf16 row-major
__global__ void transpose_cvt_kernel(const float* __restrict__ in, unsigned short* __restrict__ out,
                                     int K, int N) {
    int i = blockIdx.x * blockDim.x + threadIdx.x;
    if (i >= K * N) return;
    int k = i / N, n = i - k * N;
    out[(size_t)n * K + k] = f2bf(in[i]);
}

// ============================ attention-weight folds (direct to bf16 Bt) ============================
// layer1 al Bt [16,128]: row h<8: (W_s[128,512]·av_s)[h]; row h>=8: (W_d·av_d)[h-8]
__global__ void fold1_bt_kernel(const float* __restrict__ W_s, const float* __restrict__ av_s,
                                const float* __restrict__ W_d, const float* __restrict__ av_d,
                                unsigned short* __restrict__ out) {
    int idx = blockIdx.x * blockDim.x + threadIdx.x;
    if (idx >= 16 * 128) return;
    int h = idx >> 7, d = idx & 127;
    const float* W = (h < 8) ? W_s : W_d;
    const float* a = (h < 8) ? (av_s + h * 64) : (av_d + (h - 8) * 64);
    const float* wr = W + (size_t)d * 512 + (h & 7) * 64;
    float s = 0.f;
#pragma unroll
    for (int c = 0; c < 64; ++c) s = fmaf(wr[c], a[c], s);
    out[idx] = f2bf(s);
}

// layer2 al Bt [16,512]: row0: W_s[512,64]·av_s ; row1: W_d·av_d ; rows 2-15 zero
__global__ void fold2_bt_kernel(const float* __restrict__ W_s, const float* __restrict__ av_s,
                                const float* __restrict__ W_d, const float* __restrict__ av_d,
                                unsigned short* __restrict__ out) {
    int idx = blockIdx.x * blockDim.x + threadIdx.x;
    if (idx >= 16 * 512) return;
    int h = idx >> 9, d = idx & 511;
    float s = 0.f;
    if (h < 2) {
        const float* W = (h == 0) ? W_s : W_d;
        const float* a = (h == 0) ? av_s : av_d;
        const float* wr = W + (size_t)d * 64;
#pragma unroll
        for (int c = 0; c < 64; ++c) s = fmaf(wr[c], a[c], s);
    }
    out[idx] = f2bf(s);
}

// ============================ CSR build ============================
__global__ void hist_kernel(const int* __restrict__ dst, int E, int* __restrict__ deg) {
    int i = blockIdx.x * blockDim.x + threadIdx.x;
    if (i < E) atomicAdd(&deg[dst[i]], 1);
}

__global__ __launch_bounds__(512) void scan_chunk_kernel(const int* __restrict__ in, int N,
                                                         int* __restrict__ incl, int* __restrict__ sums) {
    __shared__ int sm[512];
    int i = blockIdx.x * 512 + threadIdx.x;
    int v = (i < N) ? in[i] : 0;
    sm[threadIdx.x] = v;
    __syncthreads();
    for (int off = 1; off < 512; off <<= 1) {
        int t = (threadIdx.x >= off) ? sm[threadIdx.x - off] : 0;
        __syncthreads();
        sm[threadIdx.x] += t;
        __syncthreads();
    }
    if (i < N) incl[i] = sm[threadIdx.x];
    if (threadIdx.x == 511) sums[blockIdx.x] = sm[511];
}

__global__ __launch_bounds__(512) void scan_sums_kernel(int* __restrict__ sums, int n) {
    __shared__ int sm[512];
    int v = (threadIdx.x < n) ? sums[threadIdx.x] : 0;
    sm[threadIdx.x] = v;
    __syncthreads();
    for (int off = 1; off < 512; off <<= 1) {
        int t = (threadIdx.x >= off) ? sm[threadIdx.x - off] : 0;
        __syncthreads();
        sm[threadIdx.x] += t;
        __syncthreads();
    }
    if (threadIdx.x < n) sums[threadIdx.x] = sm[threadIdx.x] - v;  // exclusive chunk offset
}

__global__ void scan_fin_kernel(const int* __restrict__ incl, const int* __restrict__ deg,
                                const int* __restrict__ sums, int N,
                                int* __restrict__ rowptr, int* __restrict__ cursor) {
    int i = blockIdx.x * blockDim.x + threadIdx.x;
    if (i >= N) return;
    int excl = incl[i] - deg[i] + sums[i >> 9];
    rowptr[i] = excl;
    cursor[i] = excl;
}

// scatter also records dst per CSR slot (needed by edge-parallel pe kernels)
__global__ void scatter_kernel(const int* __restrict__ src, const int* __restrict__ dst, int E,
                               int* __restrict__ cursor, int* __restrict__ csr_src,
                               int* __restrict__ csr_dst) {
    int i = blockIdx.x * blockDim.x + threadIdx.x;
    if (i >= E) return;
    int d = dst[i];
    int pos = atomicAdd(&cursor[d], 1);
    csr_src[pos] = src[i];
    csr_dst[pos] = d;
}

// ============================ edge-parallel softmax numerators ============================
// layer1: one lane per (CSR slot, head). pe[j*8+h] = exp(leaky(alsrc[sp,h] + aldst[dn,8+h]))
__global__ void edge_pe1_kernel(const int* __restrict__ csr_src, const int* __restrict__ csr_dst,
                                int E, const float* __restrict__ alsrc, const float* __restrict__ aldst,
                                float* __restrict__ pe) {
    int t = blockIdx.x * blockDim.x + threadIdx.x;
    if (t >= E * 8) return;
    int j = t >> 3, h = t & 7;
    int sp = csr_src[j], dn = csr_dst[j];
    float e = alsrc[(size_t)sp * 16 + h] + aldst[(size_t)dn * 16 + 8 + h];
    e = fmaxf(e, NEG_SLOPE * e);  // leaky relu (branchless)
    pe[t] = __expf(e);
}

// layer2 (1 head): pe[j] = exp(leaky(alsrc[sp,0] + aldst[dn,1]))
__global__ void edge_pe2_kernel(const int* __restrict__ csr_src, const int* __restrict__ csr_dst,
                                int E, const float* __restrict__ alsrc, const float* __restrict__ aldst,
                                float* __restrict__ pe) {
    int j = blockIdx.x * blockDim.x + threadIdx.x;
    if (j >= E) return;
    float e = alsrc[(size_t)csr_src[j] * 16] + aldst[(size_t)csr_dst[j] * 16 + 1];
    e = fmaxf(e, NEG_SLOPE * e);
    pe[j] = __expf(e);
}

// ============================ aggregation (plain-sum softmax) ============================
// layer1: one BLOCK (8 waves) per dst; wave h = head h. pe precomputed per (slot,head).
template <typename HT, typename OT>
__global__ __launch_bounds__(512) void agg1_kernel(
    const int* __restrict__ rowptr, const int* __restrict__ deg, const int* __restrict__ csr_src,
    const float* __restrict__ pe, const HT* __restrict__ hsrc,
    const float* __restrict__ bias, OT* __restrict__ out, int Ndst) {
    int n = blockIdx.x;
    if (n >= Ndst) return;
    int h = threadIdx.x >> 6, lane = threadIdx.x & 63;
    int start = rowptr[n], cnt = deg[n];
    const int* cs = csr_src + start;
    const float* pp = pe + (size_t)start * 8 + h;
    float s = 0.f, acc = 0.f;
    int i = 0;
    for (; i + 4 <= cnt; i += 4) {
        int sp0 = cs[i], sp1 = cs[i + 1], sp2 = cs[i + 2], sp3 = cs[i + 3];
        float p0 = pp[(size_t)i * 8], p1 = pp[(size_t)(i + 1) * 8];
        float p2 = pp[(size_t)(i + 2) * 8], p3 = pp[(size_t)(i + 3) * 8];
        float hv0 = ld1(hsrc + (size_t)sp0 * 512 + h * 64 + lane);
        float hv1 = ld1(hsrc + (size_t)sp1 * 512 + h * 64 + lane);
        float hv2 = ld1(hsrc + (size_t)sp2 * 512 + h * 64 + lane);
        float hv3 = ld1(hsrc + (size_t)sp3 * 512 + h * 64 + lane);
        s += (p0 + p1) + (p2 + p3);
        acc = fmaf(p0, hv0, acc);
        acc = fmaf(p1, hv1, acc);
        acc = fmaf(p2, hv2, acc);
        acc = fmaf(p3, hv3, acc);
    }
    for (; i < cnt; ++i) {
        int sp = cs[i];
        float p = pp[(size_t)i * 8];
        float hv = ld1(hsrc + (size_t)sp * 512 + h * 64 + lane);
        s += p;
        acc = fmaf(p, hv, acc);
    }
    float r = acc / (s + 1e-16f);
    float o = fmaxf(r + bias[h * 64 + lane], 0.f);
    st1(&out[(size_t)n * 512 + h * 64 + lane], o);
}

// layer2 (H=1,C=64): one wave per dst node. pe precomputed per slot.
template <typename HT, typename OT>
__global__ __launch_bounds__(256) void agg2_kernel(
    const int* __restrict__ rowptr, const int* __restrict__ deg, const int* __restrict__ csr_src,
    const float* __restrict__ pe, const HT* __restrict__ hsrc,
    const float* __restrict__ bias, OT* __restrict__ out, int Ndst) {
    int w = (blockIdx.x * 256 + threadIdx.x) >> 6;
    int lane = threadIdx.x & 63;
    if (w >= Ndst) return;
    int start = rowptr[w], cnt = deg[w];
    const int* cs = csr_src + start;
    const float* pp = pe + start;
    float s = 0.f, acc = 0.f;
    int i = 0;
    for (; i + 4 <= cnt; i += 4) {
        int sp0 = cs[i], sp1 = cs[i + 1], sp2 = cs[i + 2], sp3 = cs[i + 3];
        float p0 = pp[i], p1 = pp[i + 1], p2 = pp[i + 2], p3 = pp[i + 3];
        float hv0 = ld1(hsrc + (size_t)sp0 * 64 + lane);
        float hv1 = ld1(hsrc + (size_t)sp1 * 64 + lane);
        float hv2 = ld1(hsrc + (size_t)sp2 * 64 + lane);
        float hv3 = ld1(hsrc + (size_t)sp3 * 64 + lane);
        s += (p0 + p1) + (p2 + p3);
        acc = fmaf(p0, hv0, acc);
        acc = fmaf(p1, hv1, acc);
        acc = fmaf(p2, hv2, acc);
        acc = fmaf(p3, hv3, acc);
    }
    for (; i < cnt; ++i) {
        int sp = cs[i];
        float p = pp[i];
        float hv = ld1(hsrc + (size_t)sp * 64 + lane);
        s += p;
        acc = fmaf(p, hv, acc);
    }
    st1(&out[(size_t)w * 64 + lane], fmaxf(acc / (s + 1e-16f) + bias[lane], 0.f));
}

// ============================ MFMA bf16 GEMM ============================
// C[M,N] = A[M,K](bf16) @ Bt[N,K](bf16, pre-transposed) [+bias]. fp32 accum.
template <int NT, typename OT>
__global__ __launch_bounds__(256) void mfma_gemm_kernel(
    const unsigned short* __restrict__ A, const unsigned short* __restrict__ Bt,
    OT* __restrict__ C, const float* __restrict__ bias, int M, int N, int K) {
    int wave = threadIdx.x >> 6;
    int lane = threadIdx.x & 63;
    int m0 = blockIdx.x * 64 + wave * 16;
    int n0 = blockIdx.y * (NT * 16);
    int l15 = lane & 15;   // A-row within tile; C/B col within tile
    int kg = lane >> 4;    // 0..3
    f32x4 acc[NT];
#pragma unroll
    for (int t = 0; t < NT; ++t) acc[t] = (f32x4){0.f, 0.f, 0.f, 0.f};
    int arow = m0 + l15;
    const unsigned short* ap = A + (size_t)arow * K + kg * 8;
    const unsigned short* bp0 = Bt + (size_t)(n0 + l15) * K + kg * 8;
    for (int k0 = 0; k0 < K; k0 += 32) {
        bf16x8 af = {0, 0, 0, 0, 0, 0, 0, 0};
        if (arow < M) af = *(const bf16x8*)(ap + k0);
#pragma unroll
        for (int t = 0; t < NT; ++t) {
            bf16x8 bf_ = *(const bf16x8*)(bp0 + (size_t)t * 16 * K + k0);
            acc[t] = __builtin_amdgcn_mfma_f32_16x16x32_bf16(af, bf_, acc[t], 0, 0, 0);
        }
    }
    int orow0 = m0 + kg * 4;
#pragma unroll
    for (int t = 0; t < NT; ++t) {
        int ocol = n0 + t * 16 + l15;
        float bv = bias ? bias[ocol] : 0.f;
#pragma unroll
        for (int r = 0; r < 4; ++r) {
            int orow = orow0 + r;
            if (orow < M) st1(&C[(size_t)orow * N + ocol], acc[t][r] + bv);
        }
    }
}

// ============================ host launch ============================
static inline size_t align_up(size_t x, size_t a) { return (x + a - 1) / a * a; }

extern "C" void kernel_launch(void* const* d_in, const int* in_sizes, int n_in,
                              void* d_out, int out_size, void* d_ws, size_t ws_size,
                              hipStream_t stream) {
    const float* x_t = (const float*)d_in[0];
    const float* x_p = (const float*)d_in[1];
    const int* e_tp = (const int*)d_in[2];
    const int* e_pt = (const int*)d_in[3];
    const float* W1_tp = (const float*)d_in[4];
    const float* as1_tp = (const float*)d_in[5];
    const float* ad1_tp = (const float*)d_in[6];
    const float* b1_tp = (const float*)d_in[7];
    const float* W1_pt = (const float*)d_in[8];
    const float* as1_pt = (const float*)d_in[9];
    const float* ad1_pt = (const float*)d_in[10];
    const float* b1_pt = (const float*)d_in[11];
    const float* W2_tp = (const float*)d_in[12];
    const float* as2_tp = (const float*)d_in[13];
    const float* ad2_tp = (const float*)d_in[14];
    const float* b2_tp = (const float*)d_in[15];
    const float* W2_pt = (const float*)d_in[16];
    const float* as2_pt = (const float*)d_in[17];
    const float* ad2_pt = (const float*)d_in[18];
    const float* b2_pt = (const float*)d_in[19];
    const float* Wo_t = (const float*)d_in[20];
    const float* bo_t = (const float*)d_in[21];
    const float* Wo_p = (const float*)d_in[22];
    const float* bo_p = (const float*)d_in[23];

    const int Nt = in_sizes[0] / 128;
    const int Np = in_sizes[1] / 128;
    const int Etp = in_sizes[2] / 2;
    const int Ept = in_sizes[3] / 2;
    const size_t maxN = (Nt > Np) ? (size_t)Nt : (size_t)Np;

    // ---- workspace carve ----
    char* p = (char*)d_ws;
    auto alloc = [&](size_t bytes) -> void* {
        void* r = (void*)p;
        p += align_up(bytes, 256);
        return r;
    };
    // packed al arrays [N,16] f32
    float* al_t = (float*)alloc((size_t)Nt * 16 * 4);
    float* al_p = (float*)alloc((size_t)Np * 16 * 4);
    float* al2_t = (float*)alloc((size_t)Nt * 16 * 4);
    float* al2_p = (float*)alloc((size_t)Np * 16 * 4);
    // folded al weight Bt's (bf16)
    unsigned short* albt_t = (unsigned short*)alloc(16 * 128 * 2);
    unsigned short* albt_p = (unsigned short*)alloc(16 * 128 * 2);
    unsigned short* albt2_t = (unsigned short*)alloc(16 * 512 * 2);
    unsigned short* albt2_p = (unsigned short*)alloc(16 * 512 * 2);
    int* deg_p = (int*)alloc((size_t)Np * 4);
    int* rowptr_p = (int*)alloc((size_t)Np * 4);
    int* cur_p = (int*)alloc((size_t)Np * 4);
    int* incl_p = (int*)alloc((size_t)Np * 4);
    int* deg_t = (int*)alloc((size_t)Nt * 4);
    int* rowptr_t = (int*)alloc((size_t)Nt * 4);
    int* cur_t = (int*)alloc((size_t)Nt * 4);
    int* incl_t = (int*)alloc((size_t)Nt * 4);
    int* csr_tp = (int*)alloc((size_t)Etp * 4);
    int* csr_pt = (int*)alloc((size_t)Ept * 4);
    int* csrd_tp = (int*)alloc((size_t)Etp * 4);
    int* csrd_pt = (int*)alloc((size_t)Ept * 4);
    float* pe_tp = (float*)alloc((size_t)Etp * 8 * 4);  // layer1 [E,8]; layer2 reuses [E]
    float* pe_pt = (float*)alloc((size_t)Ept * 8 * 4);
    int* sums_p = (int*)alloc(512 * 4);
    int* sums_t = (int*)alloc(512 * 4);
    // bf16 operands
    unsigned short* xbf_t = (unsigned short*)alloc((size_t)Nt * 128 * 2);
    unsigned short* xbf_p = (unsigned short*)alloc((size_t)Np * 128 * 2);
    unsigned short* Bt1_tp = (unsigned short*)alloc(512 * 128 * 2);
    unsigned short* Bt1_pt = (unsigned short*)alloc(512 * 128 * 2);
    unsigned short* Bt2_tp = (unsigned short*)alloc(64 * 512 * 2);
    unsigned short* Bt2_pt = (unsigned short*)alloc(64 * 512 * 2);
    unsigned short* Bto_t = (unsigned short*)alloc(128 * 64 * 2);
    unsigned short* Bto_p = (unsigned short*)alloc(128 * 64 * 2);
    // big shared h1/h2 buffer (bf16)
    unsigned short* H = (unsigned short*)alloc(maxN * 512 * 2);
    unsigned short* p1 = (unsigned short*)alloc((size_t)Np * 512 * 2);
    unsigned short* t1 = (unsigned short*)alloc((size_t)Nt * 512 * 2);
    // layer2 sub-buffers alias H (h1 values dead by then)
    unsigned short* h2_ts = H;                              // [Nt,64]
    unsigned short* h2_ps = H + (size_t)Nt * 64;            // [Np,64]
    unsigned short* p2 = h2_ps + (size_t)Np * 64;           // [Np,64]
    unsigned short* t2 = p2 + (size_t)Np * 64;              // [Nt,64]

    if ((size_t)(p - (char*)d_ws) > ws_size) return;  // clean-fail diagnostic

    float* out_t = (float*)d_out;
    float* out_p = (float*)d_out + (size_t)Nt * 128;

    // ---- 0. zero degree arrays ----
    hipMemsetAsync(deg_p, 0, (size_t)Np * 4, stream);
    hipMemsetAsync(deg_t, 0, (size_t)Nt * 4, stream);

    // ---- 1. folds + bf16 conversions ----
    fold1_bt_kernel<<<8, 256, 0, stream>>>(W1_tp, as1_tp, W1_pt, ad1_pt, albt_t);
    fold1_bt_kernel<<<8, 256, 0, stream>>>(W1_pt, as1_pt, W1_tp, ad1_tp, albt_p);
    fold2_bt_kernel<<<32, 256, 0, stream>>>(W2_tp, as2_tp, W2_pt, ad2_pt, albt2_t);
    fold2_bt_kernel<<<32, 256, 0, stream>>>(W2_pt, as2_pt, W2_tp, ad2_tp, albt2_p);
    cvt_bf16_kernel<<<(Nt * 128 + 255) / 256, 256, 0, stream>>>(x_t, xbf_t, Nt * 128);
    cvt_bf16_kernel<<<(Np * 128 + 255) / 256, 256, 0, stream>>>(x_p, xbf_p, Np * 128);
    transpose_cvt_kernel<<<(128 * 512 + 255) / 256, 256, 0, stream>>>(W1_tp, Bt1_tp, 128, 512);
    transpose_cvt_kernel<<<(128 * 512 + 255) / 256, 256, 0, stream>>>(W1_pt, Bt1_pt, 128, 512);
    transpose_cvt_kernel<<<(512 * 64 + 255) / 256, 256, 0, stream>>>(W2_tp, Bt2_tp, 512, 64);
    transpose_cvt_kernel<<<(512 * 64 + 255) / 256, 256, 0, stream>>>(W2_pt, Bt2_pt, 512, 64);
    transpose_cvt_kernel<<<(64 * 128 + 255) / 256, 256, 0, stream>>>(Wo_t, Bto_t, 64, 128);
    transpose_cvt_kernel<<<(64 * 128 + 255) / 256, 256, 0, stream>>>(Wo_p, Bto_p, 64, 128);

    // ---- 2. al1 projections via MFMA: [N,128]@[128,16] ----
    mfma_gemm_kernel<1, float><<<dim3((Nt + 63) / 64, 1), 256, 0, stream>>>(
        xbf_t, albt_t, al_t, nullptr, Nt, 16, 128);
    mfma_gemm_kernel<1, float><<<dim3((Np + 63) / 64, 1), 256, 0, stream>>>(
        xbf_p, albt_p, al_p, nullptr, Np, 16, 128);

    // ---- 3. CSR build (dst-sorted), reused by both layers ----
    hist_kernel<<<(Etp + 255) / 256, 256, 0, stream>>>(e_tp + Etp, Etp, deg_p);
    hist_kernel<<<(Ept + 255) / 256, 256, 0, stream>>>(e_pt + Ept, Ept, deg_t);
    int nchp = (Np + 511) / 512, ncht = (Nt + 511) / 512;
    scan_chunk_kernel<<<nchp, 512, 0, stream>>>(deg_p, Np, incl_p, sums_p);
    scan_sums_kernel<<<1, 512, 0, stream>>>(sums_p, nchp);
    scan_fin_kernel<<<(Np + 255) / 256, 256, 0, stream>>>(incl_p, deg_p, sums_p, Np, rowptr_p, cur_p);
    scan_chunk_kernel<<<ncht, 512, 0, stream>>>(deg_t, Nt, incl_t, sums_t);
    scan_sums_kernel<<<1, 512, 0, stream>>>(sums_t, ncht);
    scan_fin_kernel<<<(Nt + 255) / 256, 256, 0, stream>>>(incl_t, deg_t, sums_t, Nt, rowptr_t, cur_t);
    scatter_kernel<<<(Etp + 255) / 256, 256, 0, stream>>>(e_tp, e_tp + Etp, Etp, cur_p, csr_tp, csrd_tp);
    scatter_kernel<<<(Ept + 255) / 256, 256, 0, stream>>>(e_pt, e_pt + Ept, Ept, cur_t, csr_pt, csrd_pt);

    // ---- 4. layer1 edge numerators (edge-parallel, one lane per (slot,head)) ----
    edge_pe1_kernel<<<(Etp * 8 + 255) / 256, 256, 0, stream>>>(csr_tp, csrd_tp, Etp, al_t, al_p, pe_tp);
    edge_pe1_kernel<<<(Ept * 8 + 255) / 256, 256, 0, stream>>>(csr_pt, csrd_pt, Ept, al_p, al_t, pe_pt);

    // ---- 5. layer1: h1_ts -> agg(p); h1_ps -> agg(t)  (H reused) ----
    mfma_gemm_kernel<8, unsigned short><<<dim3((Nt + 63) / 64, 4), 256, 0, stream>>>(
        xbf_t, Bt1_tp, H, nullptr, Nt, 512, 128);
    agg1_kernel<unsigned short, unsigned short><<<Np, 512, 0, stream>>>(
        rowptr_p, deg_p, csr_tp, pe_tp, H, b1_tp, p1, Np);
    mfma_gemm_kernel<8, unsigned short><<<dim3((Np + 63) / 64, 4), 256, 0, stream>>>(
        xbf_p, Bt1_pt, H, nullptr, Np, 512, 128);
    agg1_kernel<unsigned short, unsigned short><<<Nt, 512, 0, stream>>>(
        rowptr_t, deg_t, csr_pt, pe_pt, H, b1_pt, t1, Nt);

    // ---- 6. al2 projections via MFMA: [N,512]@[512,16] ----
    mfma_gemm_kernel<1, float><<<dim3((Nt + 63) / 64, 1), 256, 0, stream>>>(
        t1, albt2_t, al2_t, nullptr, Nt, 16, 512);
    mfma_gemm_kernel<1, float><<<dim3((Np + 63) / 64, 1), 256, 0, stream>>>(
        p1, albt2_p, al2_p, nullptr, Np, 16, 512);

    // ---- 7. layer2 edge numerators (reuse pe buffers; layer1 values dead) ----
    edge_pe2_kernel<<<(Etp + 255) / 256, 256, 0, stream>>>(csr_tp, csrd_tp, Etp, al2_t, al2_p, pe_tp);
    edge_pe2_kernel<<<(Ept + 255) / 256, 256, 0, stream>>>(csr_pt, csrd_pt, Ept, al2_p, al2_t, pe_pt);

    // ---- 8. layer2 GEMMs (into H head; h1 dead) ----
    mfma_gemm_kernel<4, unsigned short><<<dim3((Nt + 63) / 64, 1), 256, 0, stream>>>(
        t1, Bt2_tp, h2_ts, nullptr, Nt, 64, 512);
    mfma_gemm_kernel<4, unsigned short><<<dim3((Np + 63) / 64, 1), 256, 0, stream>>>(
        p1, Bt2_pt, h2_ps, nullptr, Np, 64, 512);

    // ---- 9. layer2 aggregation (bias+relu fused) ----
    agg2_kernel<unsigned short, unsigned short><<<(Np + 3) / 4, 256, 0, stream>>>(
        rowptr_p, deg_p, csr_tp, pe_tp, h2_ts, b2_tp, p2, Np);
    agg2_kernel<unsigned short, unsigned short><<<(Nt + 3) / 4, 256, 0, stream>>>(
        rowptr_t, deg_t, csr_pt, pe_pt, h2_ps, b2_pt, t2, Nt);

    // ---- 10. output linears (bias fused, f32 out) ----
    mfma_gemm_kernel<8, float><<<dim3((Nt + 63) / 64, 1), 256, 0, stream>>>(
        t2, Bto_t, out_t, bo_t, Nt, 128, 64);
    mfma_gemm_kernel<8, float><<<dim3((Np + 63) / 64, 1), 256, 0, stream>>>(
        p2, Bto_p, out_p, bo_p, Np, 128, 64);
}

// Round 8
// 785.427 us; speedup vs baseline: 2.2027x; 1.2100x over previous
//
#include <hip/hip_runtime.h>

#define NEG_SLOPE 0.2f

typedef __attribute__((ext_vector_type(8))) short bf16x8;
typedef __attribute__((ext_vector_type(4))) float f32x4;

// ---------------- bf16 helpers ----------------
__device__ __forceinline__ float bf2f(unsigned short u) {
    return __uint_as_float(((unsigned int)u) << 16);
}
__device__ __forceinline__ unsigned short f2bf(float f) {
    unsigned int x = __float_as_uint(f);
    x += 0x7fffu + ((x >> 16) & 1u);  // round-to-nearest-even
    return (unsigned short)(x >> 16);
}
__device__ __forceinline__ float ld1(const float* p) { return *p; }
__device__ __forceinline__ float ld1(const unsigned short* p) { return bf2f(*p); }
__device__ __forceinline__ void st1(float* p, float v) { *p = v; }
__device__ __forceinline__ void st1(unsigned short* p, float v) { *p = f2bf(v); }

// ============================ convert / transpose ============================
__global__ void cvt_bf16_kernel(const float* __restrict__ in, unsigned short* __restrict__ out, int n) {
    int i = blockIdx.x * blockDim.x + threadIdx.x;
    if (i < n) out[i] = f2bf(in[i]);
}

// in [K,N] f32 row-major -> out [N,K] bf16 row-major
__global__ void transpose_cvt_kernel(const float* __restrict__ in, unsigned short* __restrict__ out,
                                     int K, int N) {
    int i = blockIdx.x * blockDim.x + threadIdx.x;
    if (i >= K * N) return;
    int k = i / N, n = i - k * N;
    out[(size_t)n * K + k] = f2bf(in[i]);
}

// ============================ attention-weight folds (direct to bf16 Bt) ============================
// layer1 al Bt [16,128]: row h<8: (W_s[128,512]·av_s)[h]; row h>=8: (W_d·av_d)[h-8]
__global__ void fold1_bt_kernel(const float* __restrict__ W_s, const float* __restrict__ av_s,
                                const float* __restrict__ W_d, const float* __restrict__ av_d,
                                unsigned short* __restrict__ out) {
    int idx = blockIdx.x * blockDim.x + threadIdx.x;
    if (idx >= 16 * 128) return;
    int h = idx >> 7, d = idx & 127;
    const float* W = (h < 8) ? W_s : W_d;
    const float* a = (h < 8) ? (av_s + h * 64) : (av_d + (h - 8) * 64);
    const float* wr = W + (size_t)d * 512 + (h & 7) * 64;
    float s = 0.f;
#pragma unroll
    for (int c = 0; c < 64; ++c) s = fmaf(wr[c], a[c], s);
    out[idx] = f2bf(s);
}

// layer2 al Bt rows (written at +64*512 into the concat Bt): row0: W_s[512,64]·av_s ; row1: W_d·av_d ; rows 2-15 zero
__global__ void fold2_bt_kernel(const float* __restrict__ W_s, const float* __restrict__ av_s,
                                const float* __restrict__ W_d, const float* __restrict__ av_d,
                                unsigned short* __restrict__ out) {
    int idx = blockIdx.x * blockDim.x + threadIdx.x;
    if (idx >= 16 * 512) return;
    int h = idx >> 9, d = idx & 511;
    float s = 0.f;
    if (h < 2) {
        const float* W = (h == 0) ? W_s : W_d;
        const float* a = (h == 0) ? av_s : av_d;
        const float* wr = W + (size_t)d * 64;
#pragma unroll
        for (int c = 0; c < 64; ++c) s = fmaf(wr[c], a[c], s);
    }
    out[idx] = f2bf(s);
}

// ============================ CSR build ============================
__global__ void hist_kernel(const int* __restrict__ dst, int E, int* __restrict__ deg) {
    int i = blockIdx.x * blockDim.x + threadIdx.x;
    if (i < E) atomicAdd(&deg[dst[i]], 1);
}

__global__ __launch_bounds__(512) void scan_chunk_kernel(const int* __restrict__ in, int N,
                                                         int* __restrict__ incl, int* __restrict__ sums) {
    __shared__ int sm[512];
    int i = blockIdx.x * 512 + threadIdx.x;
    int v = (i < N) ? in[i] : 0;
    sm[threadIdx.x] = v;
    __syncthreads();
    for (int off = 1; off < 512; off <<= 1) {
        int t = (threadIdx.x >= off) ? sm[threadIdx.x - off] : 0;
        __syncthreads();
        sm[threadIdx.x] += t;
        __syncthreads();
    }
    if (i < N) incl[i] = sm[threadIdx.x];
    if (threadIdx.x == 511) sums[blockIdx.x] = sm[511];
}

__global__ __launch_bounds__(512) void scan_sums_kernel(int* __restrict__ sums, int n) {
    __shared__ int sm[512];
    int v = (threadIdx.x < n) ? sums[threadIdx.x] : 0;
    sm[threadIdx.x] = v;
    __syncthreads();
    for (int off = 1; off < 512; off <<= 1) {
        int t = (threadIdx.x >= off) ? sm[threadIdx.x - off] : 0;
        __syncthreads();
        sm[threadIdx.x] += t;
        __syncthreads();
    }
    if (threadIdx.x < n) sums[threadIdx.x] = sm[threadIdx.x] - v;  // exclusive chunk offset
}

__global__ void scan_fin_kernel(const int* __restrict__ incl, const int* __restrict__ deg,
                                const int* __restrict__ sums, int N,
                                int* __restrict__ rowptr, int* __restrict__ cursor) {
    int i = blockIdx.x * blockDim.x + threadIdx.x;
    if (i >= N) return;
    int excl = incl[i] - deg[i] + sums[i >> 9];
    rowptr[i] = excl;
    cursor[i] = excl;
}

// scatter also records dst per CSR slot (needed by edge-parallel pe kernels)
__global__ void scatter_kernel(const int* __restrict__ src, const int* __restrict__ dst, int E,
                               int* __restrict__ cursor, int* __restrict__ csr_src,
                               int* __restrict__ csr_dst) {
    int i = blockIdx.x * blockDim.x + threadIdx.x;
    if (i >= E) return;
    int d = dst[i];
    int pos = atomicAdd(&cursor[d], 1);
    csr_src[pos] = src[i];
    csr_dst[pos] = d;
}

// ============================ edge-parallel softmax numerators ============================
// layer1: one lane per (CSR slot, head). pe[j*8+h] = exp(leaky(alsrc[sp,h] + aldst[dn,8+h]))
__global__ void edge_pe1_kernel(const int* __restrict__ csr_src, const int* __restrict__ csr_dst,
                                int E, const float* __restrict__ alsrc, const float* __restrict__ aldst,
                                float* __restrict__ pe) {
    int t = blockIdx.x * blockDim.x + threadIdx.x;
    if (t >= E * 8) return;
    int j = t >> 3, h = t & 7;
    int sp = csr_src[j], dn = csr_dst[j];
    float e = alsrc[(size_t)sp * 16 + h] + aldst[(size_t)dn * 16 + 8 + h];
    e = fmaxf(e, NEG_SLOPE * e);  // leaky relu (branchless)
    pe[t] = __expf(e);
}

// layer2 (1 head): pe[j] = exp(leaky(alsrc[sp,0] + aldst[dn,1]))
__global__ void edge_pe2_kernel(const int* __restrict__ csr_src, const int* __restrict__ csr_dst,
                                int E, const float* __restrict__ alsrc, const float* __restrict__ aldst,
                                float* __restrict__ pe) {
    int j = blockIdx.x * blockDim.x + threadIdx.x;
    if (j >= E) return;
    float e = alsrc[(size_t)csr_src[j] * 16] + aldst[(size_t)csr_dst[j] * 16 + 1];
    e = fmaxf(e, NEG_SLOPE * e);
    pe[j] = __expf(e);
}

// ============================ aggregation (plain-sum softmax) ============================
// layer1: one WAVE per dst covering the whole 512-ch row; lane l holds channels 8l..8l+7,
// head = l>>3. Per edge: one 16B load/lane = 1KB coalesced wave request.
template <typename OT>
__global__ __launch_bounds__(256) void agg1_kernel(
    const int* __restrict__ rowptr, const int* __restrict__ deg, const int* __restrict__ csr_src,
    const float* __restrict__ pe, const unsigned short* __restrict__ hsrc,
    const float* __restrict__ bias, OT* __restrict__ out, int Ndst) {
    int w = (blockIdx.x * 256 + threadIdx.x) >> 6;
    int lane = threadIdx.x & 63;
    if (w >= Ndst) return;
    int start = rowptr[w], cnt = deg[w];
    const int* cs = csr_src + start;
    const float* pp = pe + (size_t)start * 8 + (lane >> 3);
    float acc[8] = {0.f, 0.f, 0.f, 0.f, 0.f, 0.f, 0.f, 0.f};
    float s = 0.f;
    int i = 0;
    for (; i + 4 <= cnt; i += 4) {
        int sp0 = cs[i], sp1 = cs[i + 1], sp2 = cs[i + 2], sp3 = cs[i + 3];
        float p0 = pp[(size_t)i * 8], p1 = pp[(size_t)(i + 1) * 8];
        float p2 = pp[(size_t)(i + 2) * 8], p3 = pp[(size_t)(i + 3) * 8];
        bf16x8 v0 = *(const bf16x8*)(hsrc + (size_t)sp0 * 512 + lane * 8);
        bf16x8 v1 = *(const bf16x8*)(hsrc + (size_t)sp1 * 512 + lane * 8);
        bf16x8 v2 = *(const bf16x8*)(hsrc + (size_t)sp2 * 512 + lane * 8);
        bf16x8 v3 = *(const bf16x8*)(hsrc + (size_t)sp3 * 512 + lane * 8);
        s += (p0 + p1) + (p2 + p3);
#pragma unroll
        for (int j = 0; j < 8; ++j) {
            acc[j] = fmaf(p0, bf2f((unsigned short)v0[j]), acc[j]);
            acc[j] = fmaf(p1, bf2f((unsigned short)v1[j]), acc[j]);
            acc[j] = fmaf(p2, bf2f((unsigned short)v2[j]), acc[j]);
            acc[j] = fmaf(p3, bf2f((unsigned short)v3[j]), acc[j]);
        }
    }
    for (; i < cnt; ++i) {
        int sp = cs[i];
        float p = pp[(size_t)i * 8];
        bf16x8 v = *(const bf16x8*)(hsrc + (size_t)sp * 512 + lane * 8);
        s += p;
#pragma unroll
        for (int j = 0; j < 8; ++j) acc[j] = fmaf(p, bf2f((unsigned short)v[j]), acc[j]);
    }
    float inv = 1.f / (s + 1e-16f);
    const float* bp = bias + lane * 8;
#pragma unroll
    for (int j = 0; j < 8; ++j) {
        float o = fmaxf(fmaf(acc[j], inv, 0.f) + bp[j], 0.f);
        st1(&out[(size_t)w * 512 + lane * 8 + j], o);
    }
}

// layer2 (H=1,C=64): one wave per dst; half-wave per edge (2 edges/slot), 4B/lane;
// shfl_xor(32) combines the two halves at the end.
template <typename OT>
__global__ __launch_bounds__(256) void agg2_kernel(
    const int* __restrict__ rowptr, const int* __restrict__ deg, const int* __restrict__ csr_src,
    const float* __restrict__ pe, const unsigned short* __restrict__ hsrc,
    const float* __restrict__ bias, OT* __restrict__ out, int Ndst) {
    int w = (blockIdx.x * 256 + threadIdx.x) >> 6;
    int lane = threadIdx.x & 63;
    if (w >= Ndst) return;
    int start = rowptr[w], cnt = deg[w];
    const int* cs = csr_src + start;
    const float* pp = pe + start;
    int half = lane >> 5, l32 = lane & 31;
    float a0 = 0.f, a1 = 0.f, s = 0.f;
    int i = 0;
    for (; i + 4 <= cnt; i += 4) {
        int j0 = i + half * 2;
        int sp0 = cs[j0], sp1 = cs[j0 + 1];
        float p0 = pp[j0], p1 = pp[j0 + 1];
        unsigned int v0 = *(const unsigned int*)(hsrc + (size_t)sp0 * 64 + l32 * 2);
        unsigned int v1 = *(const unsigned int*)(hsrc + (size_t)sp1 * 64 + l32 * 2);
        s += p0 + p1;
        a0 = fmaf(p0, bf2f((unsigned short)v0), a0);
        a1 = fmaf(p0, bf2f((unsigned short)(v0 >> 16)), a1);
        a0 = fmaf(p1, bf2f((unsigned short)v1), a0);
        a1 = fmaf(p1, bf2f((unsigned short)(v1 >> 16)), a1);
    }
    if (i + 2 <= cnt) {
        int j = i + half;
        int sp = cs[j];
        float p = pp[j];
        unsigned int v = *(const unsigned int*)(hsrc + (size_t)sp * 64 + l32 * 2);
        s += p;
        a0 = fmaf(p, bf2f((unsigned short)v), a0);
        a1 = fmaf(p, bf2f((unsigned short)(v >> 16)), a1);
        i += 2;
    }
    if (i < cnt && half == 0) {
        int sp = cs[i];
        float p = pp[i];
        unsigned int v = *(const unsigned int*)(hsrc + (size_t)sp * 64 + l32 * 2);
        s += p;
        a0 = fmaf(p, bf2f((unsigned short)v), a0);
        a1 = fmaf(p, bf2f((unsigned short)(v >> 16)), a1);
    }
    a0 += __shfl_xor(a0, 32);
    a1 += __shfl_xor(a1, 32);
    s += __shfl_xor(s, 32);
    if (half == 0) {
        float inv = 1.f / (s + 1e-16f);
        float o0 = fmaxf(a0 * inv + bias[l32 * 2], 0.f);
        float o1 = fmaxf(a1 * inv + bias[l32 * 2 + 1], 0.f);
        st1(&out[(size_t)w * 64 + l32 * 2], o0);
        st1(&out[(size_t)w * 64 + l32 * 2 + 1], o1);
    }
}

// ============================ MFMA bf16 GEMM ============================
// C[M,N] = A[M,K](bf16) @ Bt[N,K](bf16, pre-transposed) [+bias]. fp32 accum.
template <int NT, typename OT>
__global__ __launch_bounds__(256) void mfma_gemm_kernel(
    const unsigned short* __restrict__ A, const unsigned short* __restrict__ Bt,
    OT* __restrict__ C, const float* __restrict__ bias, int M, int N, int K) {
    int wave = threadIdx.x >> 6;
    int lane = threadIdx.x & 63;
    int m0 = blockIdx.x * 64 + wave * 16;
    int n0 = blockIdx.y * (NT * 16);
    int l15 = lane & 15;   // A-row within tile; C/B col within tile
    int kg = lane >> 4;    // 0..3
    f32x4 acc[NT];
#pragma unroll
    for (int t = 0; t < NT; ++t) acc[t] = (f32x4){0.f, 0.f, 0.f, 0.f};
    int arow = m0 + l15;
    const unsigned short* ap = A + (size_t)arow * K + kg * 8;
    const unsigned short* bp0 = Bt + (size_t)(n0 + l15) * K + kg * 8;
    for (int k0 = 0; k0 < K; k0 += 32) {
        bf16x8 af = {0, 0, 0, 0, 0, 0, 0, 0};
        if (arow < M) af = *(const bf16x8*)(ap + k0);
#pragma unroll
        for (int t = 0; t < NT; ++t) {
            bf16x8 bf_ = *(const bf16x8*)(bp0 + (size_t)t * 16 * K + k0);
            acc[t] = __builtin_amdgcn_mfma_f32_16x16x32_bf16(af, bf_, acc[t], 0, 0, 0);
        }
    }
    int orow0 = m0 + kg * 4;
#pragma unroll
    for (int t = 0; t < NT; ++t) {
        int ocol = n0 + t * 16 + l15;
        float bv = bias ? bias[ocol] : 0.f;
#pragma unroll
        for (int r = 0; r < 4; ++r) {
            int orow = orow0 + r;
            if (orow < M) st1(&C[(size_t)orow * N + ocol], acc[t][r] + bv);
        }
    }
}

// Dual-output GEMM for layer2: Btcat [80,K]: rows 0-63 = W2^T, rows 64-79 = folded att rows.
// Tiles 0-3 -> h2 (bf16, [M,64]); tile 4 -> al2 (f32, [M,16]).
__global__ __launch_bounds__(256) void mfma_gemm_dual_kernel(
    const unsigned short* __restrict__ A, const unsigned short* __restrict__ Btcat,
    unsigned short* __restrict__ Ch, float* __restrict__ Cal, int M, int K) {
    int wave = threadIdx.x >> 6;
    int lane = threadIdx.x & 63;
    int m0 = blockIdx.x * 64 + wave * 16;
    int l15 = lane & 15;
    int kg = lane >> 4;
    f32x4 acc[5];
#pragma unroll
    for (int t = 0; t < 5; ++t) acc[t] = (f32x4){0.f, 0.f, 0.f, 0.f};
    int arow = m0 + l15;
    const unsigned short* ap = A + (size_t)arow * K + kg * 8;
    const unsigned short* bp0 = Btcat + (size_t)l15 * K + kg * 8;
    for (int k0 = 0; k0 < K; k0 += 32) {
        bf16x8 af = {0, 0, 0, 0, 0, 0, 0, 0};
        if (arow < M) af = *(const bf16x8*)(ap + k0);
#pragma unroll
        for (int t = 0; t < 5; ++t) {
            bf16x8 bf_ = *(const bf16x8*)(bp0 + (size_t)t * 16 * K + k0);
            acc[t] = __builtin_amdgcn_mfma_f32_16x16x32_bf16(af, bf_, acc[t], 0, 0, 0);
        }
    }
    int orow0 = m0 + kg * 4;
#pragma unroll
    for (int t = 0; t < 4; ++t) {
        int ocol = t * 16 + l15;
#pragma unroll
        for (int r = 0; r < 4; ++r) {
            int orow = orow0 + r;
            if (orow < M) st1(&Ch[(size_t)orow * 64 + ocol], acc[t][r]);
        }
    }
#pragma unroll
    for (int r = 0; r < 4; ++r) {
        int orow = orow0 + r;
        if (orow < M) Cal[(size_t)orow * 16 + l15] = acc[4][r];
    }
}

// ============================ host launch ============================
static inline size_t align_up(size_t x, size_t a) { return (x + a - 1) / a * a; }

extern "C" void kernel_launch(void* const* d_in, const int* in_sizes, int n_in,
                              void* d_out, int out_size, void* d_ws, size_t ws_size,
                              hipStream_t stream) {
    const float* x_t = (const float*)d_in[0];
    const float* x_p = (const float*)d_in[1];
    const int* e_tp = (const int*)d_in[2];
    const int* e_pt = (const int*)d_in[3];
    const float* W1_tp = (const float*)d_in[4];
    const float* as1_tp = (const float*)d_in[5];
    const float* ad1_tp = (const float*)d_in[6];
    const float* b1_tp = (const float*)d_in[7];
    const float* W1_pt = (const float*)d_in[8];
    const float* as1_pt = (const float*)d_in[9];
    const float* ad1_pt = (const float*)d_in[10];
    const float* b1_pt = (const float*)d_in[11];
    const float* W2_tp = (const float*)d_in[12];
    const float* as2_tp = (const float*)d_in[13];
    const float* ad2_tp = (const float*)d_in[14];
    const float* b2_tp = (const float*)d_in[15];
    const float* W2_pt = (const float*)d_in[16];
    const float* as2_pt = (const float*)d_in[17];
    const float* ad2_pt = (const float*)d_in[18];
    const float* b2_pt = (const float*)d_in[19];
    const float* Wo_t = (const float*)d_in[20];
    const float* bo_t = (const float*)d_in[21];
    const float* Wo_p = (const float*)d_in[22];
    const float* bo_p = (const float*)d_in[23];

    const int Nt = in_sizes[0] / 128;
    const int Np = in_sizes[1] / 128;
    const int Etp = in_sizes[2] / 2;
    const int Ept = in_sizes[3] / 2;
    const size_t maxN = (Nt > Np) ? (size_t)Nt : (size_t)Np;

    // ---- workspace carve ----
    char* p = (char*)d_ws;
    auto alloc = [&](size_t bytes) -> void* {
        void* r = (void*)p;
        p += align_up(bytes, 256);
        return r;
    };
    // packed al arrays [N,16] f32
    float* al_t = (float*)alloc((size_t)Nt * 16 * 4);
    float* al_p = (float*)alloc((size_t)Np * 16 * 4);
    float* al2_t = (float*)alloc((size_t)Nt * 16 * 4);
    float* al2_p = (float*)alloc((size_t)Np * 16 * 4);
    // folded al weight Bt's (bf16)
    unsigned short* albt_t = (unsigned short*)alloc(16 * 128 * 2);
    unsigned short* albt_p = (unsigned short*)alloc(16 * 128 * 2);
    int* deg_p = (int*)alloc((size_t)Np * 4);
    int* rowptr_p = (int*)alloc((size_t)Np * 4);
    int* cur_p = (int*)alloc((size_t)Np * 4);
    int* incl_p = (int*)alloc((size_t)Np * 4);
    int* deg_t = (int*)alloc((size_t)Nt * 4);
    int* rowptr_t = (int*)alloc((size_t)Nt * 4);
    int* cur_t = (int*)alloc((size_t)Nt * 4);
    int* incl_t = (int*)alloc((size_t)Nt * 4);
    int* csr_tp = (int*)alloc((size_t)Etp * 4);
    int* csr_pt = (int*)alloc((size_t)Ept * 4);
    int* csrd_tp = (int*)alloc((size_t)Etp * 4);
    int* csrd_pt = (int*)alloc((size_t)Ept * 4);
    float* pe_tp = (float*)alloc((size_t)Etp * 8 * 4);  // layer1 [E,8]; layer2 reuses [E]
    float* pe_pt = (float*)alloc((size_t)Ept * 8 * 4);
    int* sums_p = (int*)alloc(512 * 4);
    int* sums_t = (int*)alloc(512 * 4);
    // bf16 operands
    unsigned short* xbf_t = (unsigned short*)alloc((size_t)Nt * 128 * 2);
    unsigned short* xbf_p = (unsigned short*)alloc((size_t)Np * 128 * 2);
    unsigned short* Bt1_tp = (unsigned short*)alloc(512 * 128 * 2);
    unsigned short* Bt1_pt = (unsigned short*)alloc(512 * 128 * 2);
    unsigned short* Btcat2_tp = (unsigned short*)alloc(80 * 512 * 2);  // [0:64)=W2^T, [64:80)=att
    unsigned short* Btcat2_pt = (unsigned short*)alloc(80 * 512 * 2);
    unsigned short* Bto_t = (unsigned short*)alloc(128 * 64 * 2);
    unsigned short* Bto_p = (unsigned short*)alloc(128 * 64 * 2);
    // big shared h1/h2 buffer (bf16)
    unsigned short* H = (unsigned short*)alloc(maxN * 512 * 2);
    unsigned short* p1 = (unsigned short*)alloc((size_t)Np * 512 * 2);
    unsigned short* t1 = (unsigned short*)alloc((size_t)Nt * 512 * 2);
    // layer2 sub-buffers alias H (h1 values dead by then)
    unsigned short* h2_ts = H;                              // [Nt,64]
    unsigned short* h2_ps = H + (size_t)Nt * 64;            // [Np,64]
    unsigned short* p2 = h2_ps + (size_t)Np * 64;           // [Np,64]
    unsigned short* t2 = p2 + (size_t)Np * 64;              // [Nt,64]

    if ((size_t)(p - (char*)d_ws) > ws_size) return;  // clean-fail diagnostic

    float* out_t = (float*)d_out;
    float* out_p = (float*)d_out + (size_t)Nt * 128;

    // ---- 0. zero degree arrays ----
    hipMemsetAsync(deg_p, 0, (size_t)Np * 4, stream);
    hipMemsetAsync(deg_t, 0, (size_t)Nt * 4, stream);

    // ---- 1. folds + bf16 conversions ----
    fold1_bt_kernel<<<8, 256, 0, stream>>>(W1_tp, as1_tp, W1_pt, ad1_pt, albt_t);
    fold1_bt_kernel<<<8, 256, 0, stream>>>(W1_pt, as1_pt, W1_tp, ad1_tp, albt_p);
    fold2_bt_kernel<<<32, 256, 0, stream>>>(W2_tp, as2_tp, W2_pt, ad2_pt, Btcat2_tp + 64 * 512);
    fold2_bt_kernel<<<32, 256, 0, stream>>>(W2_pt, as2_pt, W2_tp, ad2_tp, Btcat2_pt + 64 * 512);
    cvt_bf16_kernel<<<(Nt * 128 + 255) / 256, 256, 0, stream>>>(x_t, xbf_t, Nt * 128);
    cvt_bf16_kernel<<<(Np * 128 + 255) / 256, 256, 0, stream>>>(x_p, xbf_p, Np * 128);
    transpose_cvt_kernel<<<(128 * 512 + 255) / 256, 256, 0, stream>>>(W1_tp, Bt1_tp, 128, 512);
    transpose_cvt_kernel<<<(128 * 512 + 255) / 256, 256, 0, stream>>>(W1_pt, Bt1_pt, 128, 512);
    transpose_cvt_kernel<<<(512 * 64 + 255) / 256, 256, 0, stream>>>(W2_tp, Btcat2_tp, 512, 64);
    transpose_cvt_kernel<<<(512 * 64 + 255) / 256, 256, 0, stream>>>(W2_pt, Btcat2_pt, 512, 64);
    transpose_cvt_kernel<<<(64 * 128 + 255) / 256, 256, 0, stream>>>(Wo_t, Bto_t, 64, 128);
    transpose_cvt_kernel<<<(64 * 128 + 255) / 256, 256, 0, stream>>>(Wo_p, Bto_p, 64, 128);

    // ---- 2. al1 projections via MFMA: [N,128]@[128,16] ----
    mfma_gemm_kernel<1, float><<<dim3((Nt + 63) / 64, 1), 256, 0, stream>>>(
        xbf_t, albt_t, al_t, nullptr, Nt, 16, 128);
    mfma_gemm_kernel<1, float><<<dim3((Np + 63) / 64, 1), 256, 0, stream>>>(
        xbf_p, albt_p, al_p, nullptr, Np, 16, 128);

    // ---- 3. CSR build (dst-sorted), reused by both layers ----
    hist_kernel<<<(Etp + 255) / 256, 256, 0, stream>>>(e_tp + Etp, Etp, deg_p);
    hist_kernel<<<(Ept + 255) / 256, 256, 0, stream>>>(e_pt + Ept, Ept, deg_t);
    int nchp = (Np + 511) / 512, ncht = (Nt + 511) / 512;
    scan_chunk_kernel<<<nchp, 512, 0, stream>>>(deg_p, Np, incl_p, sums_p);
    scan_sums_kernel<<<1, 512, 0, stream>>>(sums_p, nchp);
    scan_fin_kernel<<<(Np + 255) / 256, 256, 0, stream>>>(incl_p, deg_p, sums_p, Np, rowptr_p, cur_p);
    scan_chunk_kernel<<<ncht, 512, 0, stream>>>(deg_t, Nt, incl_t, sums_t);
    scan_sums_kernel<<<1, 512, 0, stream>>>(sums_t, ncht);
    scan_fin_kernel<<<(Nt + 255) / 256, 256, 0, stream>>>(incl_t, deg_t, sums_t, Nt, rowptr_t, cur_t);
    scatter_kernel<<<(Etp + 255) / 256, 256, 0, stream>>>(e_tp, e_tp + Etp, Etp, cur_p, csr_tp, csrd_tp);
    scatter_kernel<<<(Ept + 255) / 256, 256, 0, stream>>>(e_pt, e_pt + Ept, Ept, cur_t, csr_pt, csrd_pt);

    // ---- 4. layer1 edge numerators (edge-parallel, one lane per (slot,head)) ----
    edge_pe1_kernel<<<(Etp * 8 + 255) / 256, 256, 0, stream>>>(csr_tp, csrd_tp, Etp, al_t, al_p, pe_tp);
    edge_pe1_kernel<<<(Ept * 8 + 255) / 256, 256, 0, stream>>>(csr_pt, csrd_pt, Ept, al_p, al_t, pe_pt);

    // ---- 5. layer1: h1_ts -> agg(p); h1_ps -> agg(t)  (H reused) ----
    mfma_gemm_kernel<8, unsigned short><<<dim3((Nt + 63) / 64, 4), 256, 0, stream>>>(
        xbf_t, Bt1_tp, H, nullptr, Nt, 512, 128);
    agg1_kernel<unsigned short><<<(Np + 3) / 4, 256, 0, stream>>>(
        rowptr_p, deg_p, csr_tp, pe_tp, H, b1_tp, p1, Np);
    mfma_gemm_kernel<8, unsigned short><<<dim3((Np + 63) / 64, 4), 256, 0, stream>>>(
        xbf_p, Bt1_pt, H, nullptr, Np, 512, 128);
    agg1_kernel<unsigned short><<<(Nt + 3) / 4, 256, 0, stream>>>(
        rowptr_t, deg_t, csr_pt, pe_pt, H, b1_pt, t1, Nt);

    // ---- 6. layer2 dual GEMMs: h2 + al2 in one pass over t1/p1 (into H head; h1 dead) ----
    mfma_gemm_dual_kernel<<<dim3((Nt + 63) / 64), 256, 0, stream>>>(t1, Btcat2_tp, h2_ts, al2_t, Nt, 512);
    mfma_gemm_dual_kernel<<<dim3((Np + 63) / 64), 256, 0, stream>>>(p1, Btcat2_pt, h2_ps, al2_p, Np, 512);

    // ---- 7. layer2 edge numerators (reuse pe buffers; layer1 values dead) ----
    edge_pe2_kernel<<<(Etp + 255) / 256, 256, 0, stream>>>(csr_tp, csrd_tp, Etp, al2_t, al2_p, pe_tp);
    edge_pe2_kernel<<<(Ept + 255) / 256, 256, 0, stream>>>(csr_pt, csrd_pt, Ept, al2_p, al2_t, pe_pt);

    // ---- 8. layer2 aggregation (bias+relu fused) ----
    agg2_kernel<unsigned short><<<(Np + 3) / 4, 256, 0, stream>>>(
        rowptr_p, deg_p, csr_tp, pe_tp, h2_ts, b2_tp, p2, Np);
    agg2_kernel<unsigned short><<<(Nt + 3) / 4, 256, 0, stream>>>(
        rowptr_t, deg_t, csr_pt, pe_pt, h2_ps, b2_pt, t2, Nt);

    // ---- 9. output linears (bias fused, f32 out) ----
    mfma_gemm_kernel<8, float><<<dim3((Nt + 63) / 64, 1), 256, 0, stream>>>(
        t2, Bto_t, out_t, bo_t, Nt, 128, 64);
    mfma_gemm_kernel<8, float><<<dim3((Np + 63) / 64, 1), 256, 0, stream>>>(
        p2, Bto_p, out_p, bo_p, Np, 128, 64);
}

// Round 11
// 771.621 us; speedup vs baseline: 2.2421x; 1.0179x over previous
//
#include <hip/hip_runtime.h>

#define NEG_SLOPE 0.2f

typedef __attribute__((ext_vector_type(8))) short bf16x8;
typedef __attribute__((ext_vector_type(4))) float f32x4;

// ---------------- bf16 helpers ----------------
__device__ __forceinline__ float bf2f(unsigned short u) {
    return __uint_as_float(((unsigned int)u) << 16);
}
__device__ __forceinline__ unsigned short f2bf(float f) {
    unsigned int x = __float_as_uint(f);
    x += 0x7fffu + ((x >> 16) & 1u);  // round-to-nearest-even
    return (unsigned short)(x >> 16);
}
__device__ __forceinline__ float ld1(const float* p) { return *p; }
__device__ __forceinline__ float ld1(const unsigned short* p) { return bf2f(*p); }
__device__ __forceinline__ void st1(float* p, float v) { *p = v; }
__device__ __forceinline__ void st1(unsigned short* p, float v) { *p = f2bf(v); }

// ============================ convert / transpose ============================
__global__ void cvt_bf16_kernel(const float* __restrict__ in, unsigned short* __restrict__ out, int n) {
    int i = blockIdx.x * blockDim.x + threadIdx.x;
    if (i < n) out[i] = f2bf(in[i]);
}

// in [K,N] f32 row-major -> out [N,K] bf16 row-major
__global__ void transpose_cvt_kernel(const float* __restrict__ in, unsigned short* __restrict__ out,
                                     int K, int N) {
    int i = blockIdx.x * blockDim.x + threadIdx.x;
    if (i >= K * N) return;
    int k = i / N, n = i - k * N;
    out[(size_t)n * K + k] = f2bf(in[i]);
}

// ============================ attention-weight folds (direct to bf16 Bt) ============================
// layer1 al Bt [16,128]: row h<8: (W_s[128,512]·av_s)[h]; row h>=8: (W_d·av_d)[h-8]
__global__ void fold1_bt_kernel(const float* __restrict__ W_s, const float* __restrict__ av_s,
                                const float* __restrict__ W_d, const float* __restrict__ av_d,
                                unsigned short* __restrict__ out) {
    int idx = blockIdx.x * blockDim.x + threadIdx.x;
    if (idx >= 16 * 128) return;
    int h = idx >> 7, d = idx & 127;
    const float* W = (h < 8) ? W_s : W_d;
    const float* a = (h < 8) ? (av_s + h * 64) : (av_d + (h - 8) * 64);
    const float* wr = W + (size_t)d * 512 + (h & 7) * 64;
    float s = 0.f;
#pragma unroll
    for (int c = 0; c < 64; ++c) s = fmaf(wr[c], a[c], s);
    out[idx] = f2bf(s);
}

// layer2 al Bt rows (written at +64*512 into the concat Bt): row0: W_s[512,64]·av_s ; row1: W_d·av_d ; rows 2-15 zero
__global__ void fold2_bt_kernel(const float* __restrict__ W_s, const float* __restrict__ av_s,
                                const float* __restrict__ W_d, const float* __restrict__ av_d,
                                unsigned short* __restrict__ out) {
    int idx = blockIdx.x * blockDim.x + threadIdx.x;
    if (idx >= 16 * 512) return;
    int h = idx >> 9, d = idx & 511;
    float s = 0.f;
    if (h < 2) {
        const float* W = (h == 0) ? W_s : W_d;
        const float* a = (h == 0) ? av_s : av_d;
        const float* wr = W + (size_t)d * 64;
#pragma unroll
        for (int c = 0; c < 64; ++c) s = fmaf(wr[c], a[c], s);
    }
    out[idx] = f2bf(s);
}

// ============================ CSR build ============================
__global__ void hist_kernel(const int* __restrict__ dst, int E, int* __restrict__ deg) {
    int i = blockIdx.x * blockDim.x + threadIdx.x;
    if (i < E) atomicAdd(&deg[dst[i]], 1);
}

__global__ __launch_bounds__(512) void scan_chunk_kernel(const int* __restrict__ in, int N,
                                                         int* __restrict__ incl, int* __restrict__ sums) {
    __shared__ int sm[512];
    int i = blockIdx.x * 512 + threadIdx.x;
    int v = (i < N) ? in[i] : 0;
    sm[threadIdx.x] = v;
    __syncthreads();
    for (int off = 1; off < 512; off <<= 1) {
        int t = (threadIdx.x >= off) ? sm[threadIdx.x - off] : 0;
        __syncthreads();
        sm[threadIdx.x] += t;
        __syncthreads();
    }
    if (i < N) incl[i] = sm[threadIdx.x];
    if (threadIdx.x == 511) sums[blockIdx.x] = sm[511];
}

__global__ __launch_bounds__(512) void scan_sums_kernel(int* __restrict__ sums, int n) {
    __shared__ int sm[512];
    int v = (threadIdx.x < n) ? sums[threadIdx.x] : 0;
    sm[threadIdx.x] = v;
    __syncthreads();
    for (int off = 1; off < 512; off <<= 1) {
        int t = (threadIdx.x >= off) ? sm[threadIdx.x - off] : 0;
        __syncthreads();
        sm[threadIdx.x] += t;
        __syncthreads();
    }
    if (threadIdx.x < n) sums[threadIdx.x] = sm[threadIdx.x] - v;  // exclusive chunk offset
}

__global__ void scan_fin_kernel(const int* __restrict__ incl, const int* __restrict__ deg,
                                const int* __restrict__ sums, int N,
                                int* __restrict__ rowptr, int* __restrict__ cursor) {
    int i = blockIdx.x * blockDim.x + threadIdx.x;
    if (i >= N) return;
    int excl = incl[i] - deg[i] + sums[i >> 9];
    rowptr[i] = excl;
    cursor[i] = excl;
}

// scatter also records dst per CSR slot (needed by edge-parallel pe kernels)
__global__ void scatter_kernel(const int* __restrict__ src, const int* __restrict__ dst, int E,
                               int* __restrict__ cursor, int* __restrict__ csr_src,
                               int* __restrict__ csr_dst) {
    int i = blockIdx.x * blockDim.x + threadIdx.x;
    if (i >= E) return;
    int d = dst[i];
    int pos = atomicAdd(&cursor[d], 1);
    csr_src[pos] = src[i];
    csr_dst[pos] = d;
}

// ============================ edge-parallel softmax numerators ============================
// layer1: one lane per (CSR slot, head). pe[j*8+h] = exp(leaky(alsrc[sp,h] + aldst[dn,8+h]))
__global__ void edge_pe1_kernel(const int* __restrict__ csr_src, const int* __restrict__ csr_dst,
                                int E, const float* __restrict__ alsrc, const float* __restrict__ aldst,
                                float* __restrict__ pe) {
    int t = blockIdx.x * blockDim.x + threadIdx.x;
    if (t >= E * 8) return;
    int j = t >> 3, h = t & 7;
    int sp = csr_src[j], dn = csr_dst[j];
    float e = alsrc[(size_t)sp * 16 + h] + aldst[(size_t)dn * 16 + 8 + h];
    e = fmaxf(e, NEG_SLOPE * e);  // leaky relu (branchless)
    pe[t] = __expf(e);
}

// layer2 (1 head): pe[j] = exp(leaky(alsrc[sp,0] + aldst[dn,1]))
__global__ void edge_pe2_kernel(const int* __restrict__ csr_src, const int* __restrict__ csr_dst,
                                int E, const float* __restrict__ alsrc, const float* __restrict__ aldst,
                                float* __restrict__ pe) {
    int j = blockIdx.x * blockDim.x + threadIdx.x;
    if (j >= E) return;
    float e = alsrc[(size_t)csr_src[j] * 16] + aldst[(size_t)csr_dst[j] * 16 + 1];
    e = fmaxf(e, NEG_SLOPE * e);
    pe[j] = __expf(e);
}

// ============================ aggregation (plain-sum softmax) ============================
// layer1: one WAVE per dst covering the whole 512-ch row; lane l holds channels 8l..8l+7,
// head = l>>3. Per edge: one 16B load/lane = 1KB coalesced wave request.
template <typename OT>
__global__ __launch_bounds__(256) void agg1_kernel(
    const int* __restrict__ rowptr, const int* __restrict__ deg, const int* __restrict__ csr_src,
    const float* __restrict__ pe, const unsigned short* __restrict__ hsrc,
    const float* __restrict__ bias, OT* __restrict__ out, int Ndst) {
    int w = (blockIdx.x * 256 + threadIdx.x) >> 6;
    int lane = threadIdx.x & 63;
    if (w >= Ndst) return;
    int start = rowptr[w], cnt = deg[w];
    const int* cs = csr_src + start;
    const float* pp = pe + (size_t)start * 8 + (lane >> 3);
    float acc[8] = {0.f, 0.f, 0.f, 0.f, 0.f, 0.f, 0.f, 0.f};
    float s = 0.f;
    int i = 0;
    for (; i + 4 <= cnt; i += 4) {
        int sp0 = cs[i], sp1 = cs[i + 1], sp2 = cs[i + 2], sp3 = cs[i + 3];
        float p0 = pp[(size_t)i * 8], p1 = pp[(size_t)(i + 1) * 8];
        float p2 = pp[(size_t)(i + 2) * 8], p3 = pp[(size_t)(i + 3) * 8];
        bf16x8 v0 = *(const bf16x8*)(hsrc + (size_t)sp0 * 512 + lane * 8);
        bf16x8 v1 = *(const bf16x8*)(hsrc + (size_t)sp1 * 512 + lane * 8);
        bf16x8 v2 = *(const bf16x8*)(hsrc + (size_t)sp2 * 512 + lane * 8);
        bf16x8 v3 = *(const bf16x8*)(hsrc + (size_t)sp3 * 512 + lane * 8);
        s += (p0 + p1) + (p2 + p3);
#pragma unroll
        for (int j = 0; j < 8; ++j) {
            acc[j] = fmaf(p0, bf2f((unsigned short)v0[j]), acc[j]);
            acc[j] = fmaf(p1, bf2f((unsigned short)v1[j]), acc[j]);
            acc[j] = fmaf(p2, bf2f((unsigned short)v2[j]), acc[j]);
            acc[j] = fmaf(p3, bf2f((unsigned short)v3[j]), acc[j]);
        }
    }
    for (; i < cnt; ++i) {
        int sp = cs[i];
        float p = pp[(size_t)i * 8];
        bf16x8 v = *(const bf16x8*)(hsrc + (size_t)sp * 512 + lane * 8);
        s += p;
#pragma unroll
        for (int j = 0; j < 8; ++j) acc[j] = fmaf(p, bf2f((unsigned short)v[j]), acc[j]);
    }
    float inv = 1.f / (s + 1e-16f);
    const float* bp = bias + lane * 8;
#pragma unroll
    for (int j = 0; j < 8; ++j) {
        float o = fmaxf(fmaf(acc[j], inv, 0.f) + bp[j], 0.f);
        st1(&out[(size_t)w * 512 + lane * 8 + j], o);
    }
}

// layer2 (H=1,C=64): one wave per dst; half-wave per edge (2 edges/slot), 4B/lane;
// shfl_xor(32) combines the two halves at the end.
template <typename OT>
__global__ __launch_bounds__(256) void agg2_kernel(
    const int* __restrict__ rowptr, const int* __restrict__ deg, const int* __restrict__ csr_src,
    const float* __restrict__ pe, const unsigned short* __restrict__ hsrc,
    const float* __restrict__ bias, OT* __restrict__ out, int Ndst) {
    int w = (blockIdx.x * 256 + threadIdx.x) >> 6;
    int lane = threadIdx.x & 63;
    if (w >= Ndst) return;
    int start = rowptr[w], cnt = deg[w];
    const int* cs = csr_src + start;
    const float* pp = pe + start;
    int half = lane >> 5, l32 = lane & 31;
    float a0 = 0.f, a1 = 0.f, s = 0.f;
    int i = 0;
    for (; i + 4 <= cnt; i += 4) {
        int j0 = i + half * 2;
        int sp0 = cs[j0], sp1 = cs[j0 + 1];
        float p0 = pp[j0], p1 = pp[j0 + 1];
        unsigned int v0 = *(const unsigned int*)(hsrc + (size_t)sp0 * 64 + l32 * 2);
        unsigned int v1 = *(const unsigned int*)(hsrc + (size_t)sp1 * 64 + l32 * 2);
        s += p0 + p1;
        a0 = fmaf(p0, bf2f((unsigned short)v0), a0);
        a1 = fmaf(p0, bf2f((unsigned short)(v0 >> 16)), a1);
        a0 = fmaf(p1, bf2f((unsigned short)v1), a0);
        a1 = fmaf(p1, bf2f((unsigned short)(v1 >> 16)), a1);
    }
    if (i + 2 <= cnt) {
        int j = i + half;
        int sp = cs[j];
        float p = pp[j];
        unsigned int v = *(const unsigned int*)(hsrc + (size_t)sp * 64 + l32 * 2);
        s += p;
        a0 = fmaf(p, bf2f((unsigned short)v), a0);
        a1 = fmaf(p, bf2f((unsigned short)(v >> 16)), a1);
        i += 2;
    }
    if (i < cnt && half == 0) {
        int sp = cs[i];
        float p = pp[i];
        unsigned int v = *(const unsigned int*)(hsrc + (size_t)sp * 64 + l32 * 2);
        s += p;
        a0 = fmaf(p, bf2f((unsigned short)v), a0);
        a1 = fmaf(p, bf2f((unsigned short)(v >> 16)), a1);
    }
    a0 += __shfl_xor(a0, 32);
    a1 += __shfl_xor(a1, 32);
    s += __shfl_xor(s, 32);
    if (half == 0) {
        float inv = 1.f / (s + 1e-16f);
        float o0 = fmaxf(a0 * inv + bias[l32 * 2], 0.f);
        float o1 = fmaxf(a1 * inv + bias[l32 * 2 + 1], 0.f);
        st1(&out[(size_t)w * 64 + l32 * 2], o0);
        st1(&out[(size_t)w * 64 + l32 * 2 + 1], o1);
    }
}

// ============================ MFMA bf16 GEMM (operand-swapped: computes C^T frags) ============================
// C[M,N] = A[M,K](bf16) @ Bt[N,K](bf16) [+bias]. fp32 accum. K = KSTEPS*32 compile-time.
// mfma(Bfrag, Afrag): lane l&15 -> C ROW (m0+l15); (l>>4)*4+r -> C COL (n0+t*16+kg*4+r).
// -> each lane stores 4 consecutive cols of one row: ushort4 (8B) / float4 (16B) coalesced.
template <int NT, int KSTEPS, typename OT>
__global__ __launch_bounds__(256) void mfma_gemm_kernel(
    const unsigned short* __restrict__ A, const unsigned short* __restrict__ Bt,
    OT* __restrict__ C, const float* __restrict__ bias, int M, int N) {
    constexpr int K = KSTEPS * 32;
    int wave = threadIdx.x >> 6;
    int lane = threadIdx.x & 63;
    int m0 = blockIdx.x * 64 + wave * 16;
    int n0 = blockIdx.y * (NT * 16);
    int l15 = lane & 15;
    int kg = lane >> 4;
    f32x4 acc[NT];
#pragma unroll
    for (int t = 0; t < NT; ++t) acc[t] = (f32x4){0.f, 0.f, 0.f, 0.f};
    int arow = m0 + l15;
    bool aok = arow < M;
    const unsigned short* ap = A + (size_t)arow * K + kg * 8;
    const unsigned short* bp0 = Bt + (size_t)(n0 + l15) * K + kg * 8;
#pragma unroll
    for (int ks = 0; ks < KSTEPS; ++ks) {
        int k0 = ks * 32;
        bf16x8 af = {0, 0, 0, 0, 0, 0, 0, 0};
        if (aok) af = *(const bf16x8*)(ap + k0);
#pragma unroll
        for (int t = 0; t < NT; ++t) {
            bf16x8 bf_ = *(const bf16x8*)(bp0 + (size_t)t * 16 * K + k0);
            acc[t] = __builtin_amdgcn_mfma_f32_16x16x32_bf16(bf_, af, acc[t], 0, 0, 0);
        }
    }
    if (!aok) return;
#pragma unroll
    for (int t = 0; t < NT; ++t) {
        int c0 = n0 + t * 16 + kg * 4;
        float b0 = 0.f, b1 = 0.f, b2 = 0.f, b3 = 0.f;
        if (bias) { b0 = bias[c0]; b1 = bias[c0 + 1]; b2 = bias[c0 + 2]; b3 = bias[c0 + 3]; }
        if constexpr (sizeof(OT) == 4) {
            float4 v = make_float4(acc[t][0] + b0, acc[t][1] + b1, acc[t][2] + b2, acc[t][3] + b3);
            *(float4*)&C[(size_t)arow * N + c0] = v;
        } else {
            ushort4 v;
            v.x = f2bf(acc[t][0] + b0);
            v.y = f2bf(acc[t][1] + b1);
            v.z = f2bf(acc[t][2] + b2);
            v.w = f2bf(acc[t][3] + b3);
            *(ushort4*)&C[(size_t)arow * N + c0] = v;
        }
    }
}

// Dual-output GEMM for layer2 (swapped operands, K=512): Btcat [80,512]:
// rows 0-63 = W2^T, rows 64-79 = folded att rows. Tiles 0-3 -> Ch bf16 [M,64]; tile 4 -> Cal f32 [M,16].
__global__ __launch_bounds__(256) void mfma_gemm_dual_kernel(
    const unsigned short* __restrict__ A, const unsigned short* __restrict__ Btcat,
    unsigned short* __restrict__ Ch, float* __restrict__ Cal, int M) {
    constexpr int K = 512;
    int wave = threadIdx.x >> 6;
    int lane = threadIdx.x & 63;
    int m0 = blockIdx.x * 64 + wave * 16;
    int l15 = lane & 15;
    int kg = lane >> 4;
    f32x4 acc[5];
#pragma unroll
    for (int t = 0; t < 5; ++t) acc[t] = (f32x4){0.f, 0.f, 0.f, 0.f};
    int arow = m0 + l15;
    bool aok = arow < M;
    const unsigned short* ap = A + (size_t)arow * K + kg * 8;
    const unsigned short* bp0 = Btcat + (size_t)l15 * K + kg * 8;
#pragma unroll 4
    for (int ks = 0; ks < 16; ++ks) {
        int k0 = ks * 32;
        bf16x8 af = {0, 0, 0, 0, 0, 0, 0, 0};
        if (aok) af = *(const bf16x8*)(ap + k0);
#pragma unroll
        for (int t = 0; t < 5; ++t) {
            bf16x8 bf_ = *(const bf16x8*)(bp0 + (size_t)t * 16 * K + k0);
            acc[t] = __builtin_amdgcn_mfma_f32_16x16x32_bf16(bf_, af, acc[t], 0, 0, 0);
        }
    }
    if (!aok) return;
#pragma unroll
    for (int t = 0; t < 4; ++t) {
        int c0 = t * 16 + kg * 4;
        ushort4 v;
        v.x = f2bf(acc[t][0]);
        v.y = f2bf(acc[t][1]);
        v.z = f2bf(acc[t][2]);
        v.w = f2bf(acc[t][3]);
        *(ushort4*)&Ch[(size_t)arow * 64 + c0] = v;
    }
    float4 v = make_float4(acc[4][0], acc[4][1], acc[4][2], acc[4][3]);
    *(float4*)&Cal[(size_t)arow * 16 + kg * 4] = v;
}

// ============================ host launch ============================
static inline size_t align_up(size_t x, size_t a) { return (x + a - 1) / a * a; }

extern "C" void kernel_launch(void* const* d_in, const int* in_sizes, int n_in,
                              void* d_out, int out_size, void* d_ws, size_t ws_size,
                              hipStream_t stream) {
    const float* x_t = (const float*)d_in[0];
    const float* x_p = (const float*)d_in[1];
    const int* e_tp = (const int*)d_in[2];
    const int* e_pt = (const int*)d_in[3];
    const float* W1_tp = (const float*)d_in[4];
    const float* as1_tp = (const float*)d_in[5];
    const float* ad1_tp = (const float*)d_in[6];
    const float* b1_tp = (const float*)d_in[7];
    const float* W1_pt = (const float*)d_in[8];
    const float* as1_pt = (const float*)d_in[9];
    const float* ad1_pt = (const float*)d_in[10];
    const float* b1_pt = (const float*)d_in[11];
    const float* W2_tp = (const float*)d_in[12];
    const float* as2_tp = (const float*)d_in[13];
    const float* ad2_tp = (const float*)d_in[14];
    const float* b2_tp = (const float*)d_in[15];
    const float* W2_pt = (const float*)d_in[16];
    const float* as2_pt = (const float*)d_in[17];
    const float* ad2_pt = (const float*)d_in[18];
    const float* b2_pt = (const float*)d_in[19];
    const float* Wo_t = (const float*)d_in[20];
    const float* bo_t = (const float*)d_in[21];
    const float* Wo_p = (const float*)d_in[22];
    const float* bo_p = (const float*)d_in[23];

    const int Nt = in_sizes[0] / 128;
    const int Np = in_sizes[1] / 128;
    const int Etp = in_sizes[2] / 2;
    const int Ept = in_sizes[3] / 2;
    const size_t maxN = (Nt > Np) ? (size_t)Nt : (size_t)Np;

    // ---- workspace carve ----
    char* p = (char*)d_ws;
    auto alloc = [&](size_t bytes) -> void* {
        void* r = (void*)p;
        p += align_up(bytes, 256);
        return r;
    };
    // packed al arrays [N,16] f32
    float* al_t = (float*)alloc((size_t)Nt * 16 * 4);
    float* al_p = (float*)alloc((size_t)Np * 16 * 4);
    float* al2_t = (float*)alloc((size_t)Nt * 16 * 4);
    float* al2_p = (float*)alloc((size_t)Np * 16 * 4);
    // folded al weight Bt's (bf16)
    unsigned short* albt_t = (unsigned short*)alloc(16 * 128 * 2);
    unsigned short* albt_p = (unsigned short*)alloc(16 * 128 * 2);
    int* deg_p = (int*)alloc((size_t)Np * 4);
    int* rowptr_p = (int*)alloc((size_t)Np * 4);
    int* cur_p = (int*)alloc((size_t)Np * 4);
    int* incl_p = (int*)alloc((size_t)Np * 4);
    int* deg_t = (int*)alloc((size_t)Nt * 4);
    int* rowptr_t = (int*)alloc((size_t)Nt * 4);
    int* cur_t = (int*)alloc((size_t)Nt * 4);
    int* incl_t = (int*)alloc((size_t)Nt * 4);
    int* csr_tp = (int*)alloc((size_t)Etp * 4);
    int* csr_pt = (int*)alloc((size_t)Ept * 4);
    int* csrd_tp = (int*)alloc((size_t)Etp * 4);
    int* csrd_pt = (int*)alloc((size_t)Ept * 4);
    float* pe_tp = (float*)alloc((size_t)Etp * 8 * 4);  // layer1 [E,8]; layer2 reuses [E]
    float* pe_pt = (float*)alloc((size_t)Ept * 8 * 4);
    int* sums_p = (int*)alloc(512 * 4);
    int* sums_t = (int*)alloc(512 * 4);
    // bf16 operands
    unsigned short* xbf_t = (unsigned short*)alloc((size_t)Nt * 128 * 2);
    unsigned short* xbf_p = (unsigned short*)alloc((size_t)Np * 128 * 2);
    unsigned short* Bt1_tp = (unsigned short*)alloc(512 * 128 * 2);
    unsigned short* Bt1_pt = (unsigned short*)alloc(512 * 128 * 2);
    unsigned short* Btcat2_tp = (unsigned short*)alloc(80 * 512 * 2);  // [0:64)=W2^T, [64:80)=att
    unsigned short* Btcat2_pt = (unsigned short*)alloc(80 * 512 * 2);
    unsigned short* Bto_t = (unsigned short*)alloc(128 * 64 * 2);
    unsigned short* Bto_p = (unsigned short*)alloc(128 * 64 * 2);
    // big shared h1/h2 buffer (bf16)
    unsigned short* H = (unsigned short*)alloc(maxN * 512 * 2);
    unsigned short* p1 = (unsigned short*)alloc((size_t)Np * 512 * 2);
    unsigned short* t1 = (unsigned short*)alloc((size_t)Nt * 512 * 2);
    // layer2 sub-buffers alias H (h1 values dead by then)
    unsigned short* h2_ts = H;                              // [Nt,64]
    unsigned short* h2_ps = H + (size_t)Nt * 64;            // [Np,64]
    unsigned short* p2 = h2_ps + (size_t)Np * 64;           // [Np,64]
    unsigned short* t2 = p2 + (size_t)Np * 64;              // [Nt,64]

    if ((size_t)(p - (char*)d_ws) > ws_size) return;  // clean-fail diagnostic

    float* out_t = (float*)d_out;
    float* out_p = (float*)d_out + (size_t)Nt * 128;

    // ---- 0. zero degree arrays ----
    hipMemsetAsync(deg_p, 0, (size_t)Np * 4, stream);
    hipMemsetAsync(deg_t, 0, (size_t)Nt * 4, stream);

    // ---- 1. folds + bf16 conversions ----
    fold1_bt_kernel<<<8, 256, 0, stream>>>(W1_tp, as1_tp, W1_pt, ad1_pt, albt_t);
    fold1_bt_kernel<<<8, 256, 0, stream>>>(W1_pt, as1_pt, W1_tp, ad1_tp, albt_p);
    fold2_bt_kernel<<<32, 256, 0, stream>>>(W2_tp, as2_tp, W2_pt, ad2_pt, Btcat2_tp + 64 * 512);
    fold2_bt_kernel<<<32, 256, 0, stream>>>(W2_pt, as2_pt, W2_tp, ad2_tp, Btcat2_pt + 64 * 512);
    cvt_bf16_kernel<<<(Nt * 128 + 255) / 256, 256, 0, stream>>>(x_t, xbf_t, Nt * 128);
    cvt_bf16_kernel<<<(Np * 128 + 255) / 256, 256, 0, stream>>>(x_p, xbf_p, Np * 128);
    transpose_cvt_kernel<<<(128 * 512 + 255) / 256, 256, 0, stream>>>(W1_tp, Bt1_tp, 128, 512);
    transpose_cvt_kernel<<<(128 * 512 + 255) / 256, 256, 0, stream>>>(W1_pt, Bt1_pt, 128, 512);
    transpose_cvt_kernel<<<(512 * 64 + 255) / 256, 256, 0, stream>>>(W2_tp, Btcat2_tp, 512, 64);
    transpose_cvt_kernel<<<(512 * 64 + 255) / 256, 256, 0, stream>>>(W2_pt, Btcat2_pt, 512, 64);
    transpose_cvt_kernel<<<(64 * 128 + 255) / 256, 256, 0, stream>>>(Wo_t, Bto_t, 64, 128);
    transpose_cvt_kernel<<<(64 * 128 + 255) / 256, 256, 0, stream>>>(Wo_p, Bto_p, 64, 128);

    // ---- 2. al1 projections via MFMA: [N,128]@[128,16] ----
    mfma_gemm_kernel<1, 4, float><<<dim3((Nt + 63) / 64, 1), 256, 0, stream>>>(
        xbf_t, albt_t, al_t, nullptr, Nt, 16);
    mfma_gemm_kernel<1, 4, float><<<dim3((Np + 63) / 64, 1), 256, 0, stream>>>(
        xbf_p, albt_p, al_p, nullptr, Np, 16);

    // ---- 3. CSR build (dst-sorted), reused by both layers ----
    hist_kernel<<<(Etp + 255) / 256, 256, 0, stream>>>(e_tp + Etp, Etp, deg_p);
    hist_kernel<<<(Ept + 255) / 256, 256, 0, stream>>>(e_pt + Ept, Ept, deg_t);
    int nchp = (Np + 511) / 512, ncht = (Nt + 511) / 512;
    scan_chunk_kernel<<<nchp, 512, 0, stream>>>(deg_p, Np, incl_p, sums_p);
    scan_sums_kernel<<<1, 512, 0, stream>>>(sums_p, nchp);
    scan_fin_kernel<<<(Np + 255) / 256, 256, 0, stream>>>(incl_p, deg_p, sums_p, Np, rowptr_p, cur_p);
    scan_chunk_kernel<<<ncht, 512, 0, stream>>>(deg_t, Nt, incl_t, sums_t);
    scan_sums_kernel<<<1, 512, 0, stream>>>(sums_t, ncht);
    scan_fin_kernel<<<(Nt + 255) / 256, 256, 0, stream>>>(incl_t, deg_t, sums_t, Nt, rowptr_t, cur_t);
    scatter_kernel<<<(Etp + 255) / 256, 256, 0, stream>>>(e_tp, e_tp + Etp, Etp, cur_p, csr_tp, csrd_tp);
    scatter_kernel<<<(Ept + 255) / 256, 256, 0, stream>>>(e_pt, e_pt + Ept, Ept, cur_t, csr_pt, csrd_pt);

    // ---- 4. layer1 edge numerators (edge-parallel, one lane per (slot,head)) ----
    edge_pe1_kernel<<<(Etp * 8 + 255) / 256, 256, 0, stream>>>(csr_tp, csrd_tp, Etp, al_t, al_p, pe_tp);
    edge_pe1_kernel<<<(Ept * 8 + 255) / 256, 256, 0, stream>>>(csr_pt, csrd_pt, Ept, al_p, al_t, pe_pt);

    // ---- 5. layer1: h1_ts -> agg(p); h1_ps -> agg(t)  (H reused) ----
    mfma_gemm_kernel<8, 4, unsigned short><<<dim3((Nt + 63) / 64, 4), 256, 0, stream>>>(
        xbf_t, Bt1_tp, H, nullptr, Nt, 512);
    agg1_kernel<unsigned short><<<(Np + 3) / 4, 256, 0, stream>>>(
        rowptr_p, deg_p, csr_tp, pe_tp, H, b1_tp, p1, Np);
    mfma_gemm_kernel<8, 4, unsigned short><<<dim3((Np + 63) / 64, 4), 256, 0, stream>>>(
        xbf_p, Bt1_pt, H, nullptr, Np, 512);
    agg1_kernel<unsigned short><<<(Nt + 3) / 4, 256, 0, stream>>>(
        rowptr_t, deg_t, csr_pt, pe_pt, H, b1_pt, t1, Nt);

    // ---- 6. layer2 dual GEMMs: h2 + al2 in one pass over t1/p1 (into H head; h1 dead) ----
    mfma_gemm_dual_kernel<<<dim3((Nt + 63) / 64), 256, 0, stream>>>(t1, Btcat2_tp, h2_ts, al2_t, Nt);
    mfma_gemm_dual_kernel<<<dim3((Np + 63) / 64), 256, 0, stream>>>(p1, Btcat2_pt, h2_ps, al2_p, Np);

    // ---- 7. layer2 edge numerators (reuse pe buffers; layer1 values dead) ----
    edge_pe2_kernel<<<(Etp + 255) / 256, 256, 0, stream>>>(csr_tp, csrd_tp, Etp, al2_t, al2_p, pe_tp);
    edge_pe2_kernel<<<(Ept + 255) / 256, 256, 0, stream>>>(csr_pt, csrd_pt, Ept, al2_p, al2_t, pe_pt);

    // ---- 8. layer2 aggregation (bias+relu fused) ----
    agg2_kernel<unsigned short><<<(Np + 3) / 4, 256, 0, stream>>>(
        rowptr_p, deg_p, csr_tp, pe_tp, h2_ts, b2_tp, p2, Np);
    agg2_kernel<unsigned short><<<(Nt + 3) / 4, 256, 0, stream>>>(
        rowptr_t, deg_t, csr_pt, pe_pt, h2_ps, b2_pt, t2, Nt);

    // ---- 9. output linears (bias fused, f32 out) ----
    mfma_gemm_kernel<8, 2, float><<<dim3((Nt + 63) / 64, 1), 256, 0, stream>>>(
        t2, Bto_t, out_t, bo_t, Nt, 128);
    mfma_gemm_kernel<8, 2, float><<<dim3((Np + 63) / 64, 1), 256, 0, stream>>>(
        p2, Bto_p, out_p, bo_p, Np, 128);
}